// Round 17
// baseline (534.761 us; speedup 1.0000x reference)
//
#include <hip/hip_runtime.h>

#define BATCH 16
#define CH 512
#define OC 1536
#define KDIM 1024
#define LMAX 4096
#define WGLOB_SZ 3145728  // 16 steps * 1536 rows * 128 B (fp16, 64 k per step)

typedef __attribute__((ext_vector_type(8))) _Float16 h8v;
typedef __attribute__((ext_vector_type(4))) float f4v;

__device__ __forceinline__ int nfp2_of(int n) { return 1 << (31 - __clz(n)); }

__device__ __forceinline__ unsigned short h2u(_Float16 h) {
  union { _Float16 h; unsigned short u; } v; v.h = h; return v.u;
}

// per-batch arena layout; records are 2KB (1024 fp16)
// record: chunk = k>>6 (128 B), slot s in chunk holds k-octant (s ^ (d&7)), 8 fp16
__device__ __forceinline__ void layout(const int* __restrict__ Nvec, int b,
                                       size_t& offC0, size_t& offA, size_t& offB,
                                       int& n, int& nfp2, int& half) {
  size_t c0t = 0, at = 0, bt = 0, c0o = 0, ao = 0, bo = 0;
  n = 2; nfp2 = 2; half = 0;
#pragma unroll 1
  for (int i = 0; i < BATCH; ++i) {
    int ni = Nvec[i];
    int f = nfp2_of(ni);
    int hf = ni - f;
    size_t cs = (size_t)((hf + 127) & ~127) << 11;
    size_t as = (size_t)(f >> 1) << 11;
    size_t bs = (size_t)(f >> 2) << 11;
    if (i < b) { c0o += cs; ao += as; bo += bs; }
    if (i == b) { n = ni; nfp2 = f; half = hf; }
    c0t += cs; at += as; bt += bs;
  }
  offC0 = (size_t)WGLOB_SZ + c0o;
  offA = (size_t)WGLOB_SZ + c0t + ao;
  offB = (size_t)WGLOB_SZ + c0t + at + bo;
}

__device__ __forceinline__ void gload16(const void* g, void* l) {
  __builtin_amdgcn_global_load_lds((const __attribute__((address_space(1))) void*)g,
                                   (__attribute__((address_space(3))) void*)l, 16, 0, 0);
}

// ---------- W prep: W[o][k] fp32 -> Wglob[step][o][128 B], slot s = octant s^(o&7) ----------
__global__ __launch_bounds__(256) void prep_w_k(const float* __restrict__ W, char* __restrict__ ws) {
  int idx = blockIdx.x * 256 + threadIdx.x;  // idx = step*1536 + o
  if (idx >= 16 * 1536) return;
  int step = idx / 1536;
  int o = idx - step * 1536;
  const float* src = W + (size_t)o * KDIM + step * 64;
  unsigned short hb[64];
#pragma unroll
  for (int t = 0; t < 64; ++t) hb[t] = h2u((_Float16)src[t]);
  uint4* d4 = (uint4*)(ws + ((size_t)idx << 7));
#pragma unroll
  for (int s = 0; s < 8; ++s) {
    int oc = (s ^ (o & 7)) * 8;
    uint4 v;
    v.x = (unsigned)hb[oc + 0] | ((unsigned)hb[oc + 1] << 16);
    v.y = (unsigned)hb[oc + 2] | ((unsigned)hb[oc + 3] << 16);
    v.z = (unsigned)hb[oc + 4] | ((unsigned)hb[oc + 5] << 16);
    v.w = (unsigned)hb[oc + 6] | ((unsigned)hb[oc + 7] << 16);
    d4[s] = v;
  }
}

// ---------- h reorg: coalesced read + LDS transpose -> fp16 records ----------
__global__ __launch_bounds__(256) void reorg_h_k(const float* __restrict__ h,
                                                 const int* __restrict__ Nvec,
                                                 char* __restrict__ ws,
                                                 float* __restrict__ dout, int mode) {
  __shared__ char T[32 * 256];  // 8 KB
  const int b = blockIdx.z;
  size_t offC0, offA, offB; int n, nfp2, half;
  layout(Nvec, b, offC0, offA, offB, n, nfp2, half);
  const int tid = threadIdx.x;
  const int by = blockIdx.y;
  const int c0 = by * 64;

  if (mode == 1 && nfp2 == 1) {  // degenerate: answer is h[:, 0]
    if (blockIdx.x == 0 && tid < 64)
      dout[(size_t)b * CH + c0 + tid] = h[(size_t)b * CH * LMAX + (size_t)(c0 + tid) * LMAX];
    return;
  }

  const int d0 = blockIdx.x * 32;
  int dlo, dhi, soff;
  size_t base;
  if (mode == 0) { dlo = 0; dhi = half; soff = 0; base = offC0; }
  else { dlo = half >> 1; dhi = nfp2 >> 1; soff = half; base = offA; }
  if (d0 >= dhi || d0 + 32 <= dlo) return;

  const float* hb = h + (size_t)b * CH * LMAX;

#pragma unroll
  for (int q = 0; q < 8; ++q) {
    int id = q * 256 + tid;
    int cl = id >> 5;
    int dl = id & 31;
    int d = d0 + dl;
    bool ok = (d < dhi) && (d >= dlo);
    float2 v;
    v.x = 0.f; v.y = 0.f;
    if (ok) v = *(const float2*)(hb + (size_t)(c0 + cl) * LMAX + 2 * d + soff);
    unsigned u = (unsigned)h2u((_Float16)v.x) | ((unsigned)h2u((_Float16)v.y) << 16);
    int g = cl >> 2;
    *(unsigned*)(T + dl * 256 + ((g ^ (dl & 15)) << 4) + (cl & 3) * 4) = u;
  }
  __syncthreads();
#pragma unroll
  for (int qq = 0; qq < 2; ++qq) {
    int gid = qq * 256 + tid;
    int dl = gid >> 4;
    int s = gid & 15;
    int d = d0 + dl;
    if (d >= dhi || d < dlo) continue;
    uint4 val = *(const uint4*)(T + dl * 256 + ((s ^ (dl & 15)) << 4));
    size_t dst = base + ((size_t)d << 11) + (size_t)((2 * by + (s >> 3)) << 7) +
                 (((s & 7) ^ (d & 7)) << 4);
    *(uint4*)(ws + dst) = val;
  }
}

// ---------- big levels (0..4): fp16 MFMA GEMM + fused gate ----------
// 192x128 tile, 256 threads, 4 waves = 2 ch-groups x 2 col-groups. BK=128 (8 steps):
// halves the number of per-step barrier-drain exposures vs BK=64 (the binding term).
// LDS = 2 x (A 48K + B 32K) = 160 KB (full pool, 1 block/CU).
__global__ __launch_bounds__(256, 2) void mfma_level_k(const float* __restrict__ bias,
                                                       const int* __restrict__ Nvec,
                                                       char* __restrict__ ws,
                                                       float* __restrict__ dout,
                                                       int level, int tiles) {
  __shared__ char smem[163840];  // A: 2 x 49152 @0, B: 2 x 32768 @98304
  const int id = blockIdx.x;
  const int o0 = (id & 7) * 64;   // o-group pinned to XCD via id%8 (W slice L2-resident)
  const int r2 = id >> 3;
  const int xb = r2 % tiles;
  const int b = r2 / tiles;
  if (b >= BATCH) return;

  size_t offC0, offA, offB; int n, nfp2, half;
  layout(Nvec, b, offC0, offA, offB, n, nfp2, half);

  int cols;
  size_t inOff, outOff;
  if (level == 0) {
    if (half == 0) return;
    cols = half;
    inOff = offC0;
    outOff = offA;
  } else {
    int w = nfp2 >> (level - 1);
    if (w < 2) return;
    cols = w >> 1;
    inOff = (level & 1) ? offA : offB;
    outOff = (level & 1) ? offB : offA;
  }
  const bool fin = (level > 0) && ((nfp2 >> level) == 1);
  const int l0 = xb * 128;
  if (l0 >= cols) return;

  const int tid = threadIdx.x;
  const int lane = tid & 63, wid = tid >> 6;
  const int lane15 = lane & 15, lq = lane >> 4;
  const int rg = wid & 1, cg = wid >> 1;   // cg in {0,1}
  const char* inp = ws + inOff;

  // A: 192 rows x 256 B (two 64-k chunks per row), chunk = byte>>7
  unsigned aoff[12]; int adst[12];
#pragma unroll
  for (int q = 0; q < 12; ++q) {
    int d = q * 4096 + tid * 16;
    int r = d >> 8;                               // tile row 0..191
    int p = d & 255;
    int o = ((r >> 6) << 9) + o0 + (r & 63);      // global output row
    aoff[q] = (unsigned)(p >> 7) * 196608u + ((unsigned)o << 7) + (p & 127);
    adst[q] = q * 4096 + wid * 1024;
  }
  // B: 128 cols x 256 B
  unsigned boff[8]; int bdst[8];
#pragma unroll
  for (int q = 0; q < 8; ++q) {
    int d = q * 4096 + tid * 16;
    int l = d >> 8;                               // col within tile 0..127
    int p = d & 255;
    int lc = l0 + l; if (lc > cols - 1) lc = cols - 1;
    boff[q] = ((unsigned)lc << 11) + (unsigned)((p >> 7) << 7) + (p & 127);
    bdst[q] = q * 4096 + wid * 1024;
  }

#define STAGE(st, sel) do {                                                  \
    char* Ab = smem + (sel) * 49152;                                         \
    char* Bb = smem + 98304 + (sel) * 32768;                                 \
    unsigned ka = (unsigned)(st) * 393216u;                                  \
    unsigned kb = (unsigned)(st) << 8;                                       \
    _Pragma("unroll") for (int q = 0; q < 12; ++q)                           \
      gload16(ws + ka + aoff[q], Ab + adst[q]);                              \
    _Pragma("unroll") for (int q = 0; q < 8; ++q)                            \
      gload16(inp + kb + boff[q], Bb + bdst[q]);                             \
  } while (0)

  f4v acc[6][4];
#pragma unroll
  for (int m = 0; m < 6; ++m)
#pragma unroll
    for (int cf = 0; cf < 4; ++cf) acc[m][cf] = (f4v){0.f, 0.f, 0.f, 0.f};

  STAGE(0, 0);
  __syncthreads();

#pragma unroll 1
  for (int st = 0; st < 8; ++st) {
    const int cur = st & 1;
    if (st + 1 < 8) STAGE(st + 1, cur ^ 1);  // prefetch overlaps this step's compute
    const char* Asb = smem + cur * 49152;
    const char* Bsb = smem + 98304 + cur * 32768;

#pragma unroll
    for (int sub = 0; sub < 2; ++sub) {
#pragma unroll
      for (int s2 = 0; s2 < 2; ++s2) {
        const int oct = (s2 << 2) | lq;           // k-octant within the 64-k chunk
        h8v bh[4];
#pragma unroll
        for (int cf = 0; cf < 4; ++cf) {
          int ll = cg * 64 + cf * 16 + lane15;
          bh[cf] = *(const h8v*)(Bsb + ll * 256 + sub * 128 + ((oct ^ (ll & 7)) << 4));
        }
#pragma unroll
        for (int m = 0; m < 6; ++m) {
          int rr = (m >> 1) * 64 + rg * 32 + (m & 1) * 16 + lane15;
          h8v ah = *(const h8v*)(Asb + rr * 256 + sub * 128 + ((oct ^ (rr & 7)) << 4));
#pragma unroll
          for (int cf = 0; cf < 4; ++cf)
            acc[m][cf] = __builtin_amdgcn_mfma_f32_16x16x32_f16(ah, bh[cf], acc[m][cf], 0, 0, 0);
        }
      }
    }
    __syncthreads();
  }
#undef STAGE

  // epilogue
  char* outp = ws + outOff;
#pragma unroll
  for (int s = 0; s < 2; ++s) {
#pragma unroll
    for (int cf = 0; cf < 4; ++cf) {
      f4v vl = acc[s][cf], vr = acc[2 + s][cf], vg = acc[4 + s][cf];
      int l = l0 + cg * 64 + cf * 16 + lane15;
      if (l >= cols) continue;
      int P = l >> 1, par = l & 1;
#pragma unroll
      for (int j = 0; j < 4; ++j) {
        int c = o0 + rg * 32 + s * 16 + lq * 4 + j;
        float zl = vl[j] + bias[c];
        float zr = vr[j] + bias[CH + c];
        float zg = vg[j] + bias[2 * CH + c];
        float g = 1.f / (1.f + __expf(-zg));
        float rt = 1.f - 2.f / (1.f + __expf(2.f * zr));
        float val = zl * g + rt * (1.f - g);
        if (fin) {
          if (l == 0) dout[(size_t)b * CH + c] = val;
        } else {
          int k = 2 * c + par;
          size_t byte = ((size_t)P << 11) + (size_t)((k >> 6) << 7) +
                        ((((k >> 3) & 7) ^ (P & 7)) << 4) + ((k & 7) << 1);
          *(unsigned short*)(outp + byte) = h2u((_Float16)val);
        }
      }
    }
  }
}

// ---------- small levels (5..12, cols <= 128): BK=128, 192x64 tile (r14, proven) ----------
__global__ __launch_bounds__(256, 2) void small_level_k(const float* __restrict__ bias,
                                                        const int* __restrict__ Nvec,
                                                        char* __restrict__ ws,
                                                        float* __restrict__ dout,
                                                        int level, int tiles) {
  __shared__ char smem[131072];  // A: 2 x 49152 @0, B: 2 x 16384 @98304
  const int id = blockIdx.x;
  const int o0 = (id & 7) * 64;
  const int r2 = id >> 3;
  const int xb = r2 % tiles;
  const int b = r2 / tiles;
  if (b >= BATCH) return;

  size_t offC0, offA, offB; int n, nfp2, half;
  layout(Nvec, b, offC0, offA, offB, n, nfp2, half);

  int w = nfp2 >> (level - 1);
  if (w < 2) return;
  const int cols = w >> 1;
  const size_t inOff = (level & 1) ? offA : offB;
  const size_t outOff = (level & 1) ? offB : offA;
  const bool fin = (cols == 1);
  const int l0 = xb * 64;
  if (l0 >= cols) return;

  const int tid = threadIdx.x;
  const int lane = tid & 63, wid = tid >> 6;
  const int lane15 = lane & 15, lq = lane >> 4;
  const int rg = wid & 1, cg = wid >> 1;
  const char* inp = ws + inOff;

  unsigned aoff[12]; int adst[12];
#pragma unroll
  for (int q = 0; q < 12; ++q) {
    int d = q * 4096 + tid * 16;
    int r = d >> 8;                               // tile row 0..191 (256 B rows)
    int p = d & 255;
    int o = ((r >> 6) << 9) + o0 + (r & 63);
    aoff[q] = (unsigned)(p >> 7) * 196608u + ((unsigned)o << 7) + (p & 127);
    adst[q] = q * 4096 + wid * 1024;
  }
  unsigned boff[4]; int bdst[4];
#pragma unroll
  for (int q = 0; q < 4; ++q) {
    int d = q * 4096 + tid * 16;
    int l = d >> 8;                               // col 0..63
    int p = d & 255;
    int lc = l0 + l; if (lc > cols - 1) lc = cols - 1;
    boff[q] = ((unsigned)lc << 11) + (unsigned)((p >> 7) << 7) + (p & 127);
    bdst[q] = q * 4096 + wid * 1024;
  }

#define STAGES(st, sel) do {                                                 \
    char* Ab = smem + (sel) * 49152;                                         \
    char* Bb = smem + 98304 + (sel) * 16384;                                 \
    unsigned ka = (unsigned)(st) * 393216u;                                  \
    unsigned kb = (unsigned)(st) << 8;                                       \
    _Pragma("unroll") for (int q = 0; q < 12; ++q)                           \
      gload16(ws + ka + aoff[q], Ab + adst[q]);                              \
    _Pragma("unroll") for (int q = 0; q < 4; ++q)                            \
      gload16(inp + kb + boff[q], Bb + bdst[q]);                             \
  } while (0)

  f4v acc[6][2];
#pragma unroll
  for (int m = 0; m < 6; ++m)
#pragma unroll
    for (int cf = 0; cf < 2; ++cf) acc[m][cf] = (f4v){0.f, 0.f, 0.f, 0.f};

  STAGES(0, 0);
  __syncthreads();

#pragma unroll 1
  for (int st = 0; st < 8; ++st) {
    const int cur = st & 1;
    if (st + 1 < 8) STAGES(st + 1, cur ^ 1);
    const char* Asb = smem + cur * 49152;
    const char* Bsb = smem + 98304 + cur * 16384;

#pragma unroll
    for (int sub = 0; sub < 2; ++sub) {
#pragma unroll
      for (int s2 = 0; s2 < 2; ++s2) {
        const int oct = (s2 << 2) | lq;
        h8v bh[2];
#pragma unroll
        for (int cf = 0; cf < 2; ++cf) {
          int ll = cg * 32 + cf * 16 + lane15;
          bh[cf] = *(const h8v*)(Bsb + ll * 256 + sub * 128 + ((oct ^ (ll & 7)) << 4));
        }
#pragma unroll
        for (int m = 0; m < 6; ++m) {
          int rr = (m >> 1) * 64 + rg * 32 + (m & 1) * 16 + lane15;
          h8v ah = *(const h8v*)(Asb + rr * 256 + sub * 128 + ((oct ^ (rr & 7)) << 4));
#pragma unroll
          for (int cf = 0; cf < 2; ++cf)
            acc[m][cf] = __builtin_amdgcn_mfma_f32_16x16x32_f16(ah, bh[cf], acc[m][cf], 0, 0, 0);
        }
      }
    }
    __syncthreads();
  }
#undef STAGES

  char* outp = ws + outOff;
#pragma unroll
  for (int s = 0; s < 2; ++s) {
#pragma unroll
    for (int cf = 0; cf < 2; ++cf) {
      f4v vl = acc[s][cf], vr = acc[2 + s][cf], vg = acc[4 + s][cf];
      int l = l0 + cg * 32 + cf * 16 + lane15;
      if (l >= cols) continue;
      int P = l >> 1, par = l & 1;
#pragma unroll
      for (int j = 0; j < 4; ++j) {
        int c = o0 + rg * 32 + s * 16 + lq * 4 + j;
        float zl = vl[j] + bias[c];
        float zr = vr[j] + bias[CH + c];
        float zg = vg[j] + bias[2 * CH + c];
        float g = 1.f / (1.f + __expf(-zg));
        float rt = 1.f - 2.f / (1.f + __expf(2.f * zr));
        float val = zl * g + rt * (1.f - g);
        if (fin) {
          if (l == 0) dout[(size_t)b * CH + c] = val;
        } else {
          int k = 2 * c + par;
          size_t byte = ((size_t)P << 11) + (size_t)((k >> 6) << 7) +
                        ((((k >> 3) & 7) ^ (P & 7)) << 4) + ((k & 7) << 1);
          *(unsigned short*)(outp + byte) = h2u((_Float16)val);
        }
      }
    }
  }
}

extern "C" void kernel_launch(void* const* d_in, const int* in_sizes, int n_in,
                              void* d_out, int out_size, void* d_ws, size_t ws_size,
                              hipStream_t stream) {
  const float* h = (const float*)d_in[0];
  const float* W = (const float*)d_in[1];
  const float* bias = (const float*)d_in[2];
  const int* Nvec = (const int*)d_in[3];
  float* dout = (float*)d_out;
  char* ws = (char*)d_ws;

  prep_w_k<<<dim3(96), 256, 0, stream>>>(W, ws);
  reorg_h_k<<<dim3(64, 8, BATCH), 256, 0, stream>>>(h, Nvec, ws, dout, 0);
  reorg_h_k<<<dim3(64, 8, BATCH), 256, 0, stream>>>(h, Nvec, ws, dout, 1);

  // level 0: max half = 952 -> 8 tiles of 128
  mfma_level_k<<<dim3(8 * 8 * BATCH), 256, 0, stream>>>(bias, Nvec, ws, dout, 0, 8);
  // big tree levels 1..4 (cols up to 2048), 128-col tiles
  for (int lev = 1; lev <= 4; ++lev) {
    int tiles = (LMAX >> lev) / 128;
    mfma_level_k<<<dim3(tiles * 8 * BATCH), 256, 0, stream>>>(bias, Nvec, ws, dout, lev, tiles);
  }
  // small tree levels 5..12 (cols <= 128): BK=128 kernel, 64-col tiles
  for (int lev = 5; lev <= 12; ++lev) {
    int colsmax = LMAX >> lev;
    int tiles = (colsmax + 63) / 64; if (tiles < 1) tiles = 1;
    small_level_k<<<dim3(tiles * 8 * BATCH), 256, 0, stream>>>(bias, Nvec, ws, dout, lev, tiles);
  }
}

// Round 18
// 513.090 us; speedup vs baseline: 1.0422x; 1.0422x over previous
//
#include <hip/hip_runtime.h>

#define BATCH 16
#define CH 512
#define OC 1536
#define KDIM 1024
#define LMAX 4096
#define WGLOB_SZ 3145728  // 16 steps * 1536 rows * 128 B (fp16, 64 k per step)

typedef __attribute__((ext_vector_type(8))) _Float16 h8v;
typedef __attribute__((ext_vector_type(4))) float f4v;

__device__ __forceinline__ int nfp2_of(int n) { return 1 << (31 - __clz(n)); }

__device__ __forceinline__ unsigned short h2u(_Float16 h) {
  union { _Float16 h; unsigned short u; } v; v.h = h; return v.u;
}

// per-batch arena layout; records are 2KB (1024 fp16)
// record: chunk = k>>6 (128 B), slot s in chunk holds k-octant (s ^ (d&7)), 8 fp16
__device__ __forceinline__ void layout(const int* __restrict__ Nvec, int b,
                                       size_t& offC0, size_t& offA, size_t& offB,
                                       int& n, int& nfp2, int& half) {
  size_t c0t = 0, at = 0, bt = 0, c0o = 0, ao = 0, bo = 0;
  n = 2; nfp2 = 2; half = 0;
#pragma unroll 1
  for (int i = 0; i < BATCH; ++i) {
    int ni = Nvec[i];
    int f = nfp2_of(ni);
    int hf = ni - f;
    size_t cs = (size_t)((hf + 127) & ~127) << 11;
    size_t as = (size_t)(f >> 1) << 11;
    size_t bs = (size_t)(f >> 2) << 11;
    if (i < b) { c0o += cs; ao += as; bo += bs; }
    if (i == b) { n = ni; nfp2 = f; half = hf; }
    c0t += cs; at += as; bt += bs;
  }
  offC0 = (size_t)WGLOB_SZ + c0o;
  offA = (size_t)WGLOB_SZ + c0t + ao;
  offB = (size_t)WGLOB_SZ + c0t + at + bo;
}

__device__ __forceinline__ void gload16(const void* g, void* l) {
  __builtin_amdgcn_global_load_lds((const __attribute__((address_space(1))) void*)g,
                                   (__attribute__((address_space(3))) void*)l, 16, 0, 0);
}

// ---------- W prep: W[o][k] fp32 -> Wglob[step][o][128 B], slot s = octant s^(o&7) ----------
__global__ __launch_bounds__(256) void prep_w_k(const float* __restrict__ W, char* __restrict__ ws) {
  int idx = blockIdx.x * 256 + threadIdx.x;  // idx = step*1536 + o
  if (idx >= 16 * 1536) return;
  int step = idx / 1536;
  int o = idx - step * 1536;
  const float* src = W + (size_t)o * KDIM + step * 64;
  unsigned short hb[64];
#pragma unroll
  for (int t = 0; t < 64; ++t) hb[t] = h2u((_Float16)src[t]);
  uint4* d4 = (uint4*)(ws + ((size_t)idx << 7));
#pragma unroll
  for (int s = 0; s < 8; ++s) {
    int oc = (s ^ (o & 7)) * 8;
    uint4 v;
    v.x = (unsigned)hb[oc + 0] | ((unsigned)hb[oc + 1] << 16);
    v.y = (unsigned)hb[oc + 2] | ((unsigned)hb[oc + 3] << 16);
    v.z = (unsigned)hb[oc + 4] | ((unsigned)hb[oc + 5] << 16);
    v.w = (unsigned)hb[oc + 6] | ((unsigned)hb[oc + 7] << 16);
    d4[s] = v;
  }
}

// ---------- h reorg: coalesced read + LDS transpose -> fp16 records ----------
__global__ __launch_bounds__(256) void reorg_h_k(const float* __restrict__ h,
                                                 const int* __restrict__ Nvec,
                                                 char* __restrict__ ws,
                                                 float* __restrict__ dout, int mode) {
  __shared__ char T[32 * 256];  // 8 KB
  const int b = blockIdx.z;
  size_t offC0, offA, offB; int n, nfp2, half;
  layout(Nvec, b, offC0, offA, offB, n, nfp2, half);
  const int tid = threadIdx.x;
  const int by = blockIdx.y;
  const int c0 = by * 64;

  if (mode == 1 && nfp2 == 1) {  // degenerate: answer is h[:, 0]
    if (blockIdx.x == 0 && tid < 64)
      dout[(size_t)b * CH + c0 + tid] = h[(size_t)b * CH * LMAX + (size_t)(c0 + tid) * LMAX];
    return;
  }

  const int d0 = blockIdx.x * 32;
  int dlo, dhi, soff;
  size_t base;
  if (mode == 0) { dlo = 0; dhi = half; soff = 0; base = offC0; }
  else { dlo = half >> 1; dhi = nfp2 >> 1; soff = half; base = offA; }
  if (d0 >= dhi || d0 + 32 <= dlo) return;

  const float* hb = h + (size_t)b * CH * LMAX;

#pragma unroll
  for (int q = 0; q < 8; ++q) {
    int id = q * 256 + tid;
    int cl = id >> 5;
    int dl = id & 31;
    int d = d0 + dl;
    bool ok = (d < dhi) && (d >= dlo);
    float2 v;
    v.x = 0.f; v.y = 0.f;
    if (ok) v = *(const float2*)(hb + (size_t)(c0 + cl) * LMAX + 2 * d + soff);
    unsigned u = (unsigned)h2u((_Float16)v.x) | ((unsigned)h2u((_Float16)v.y) << 16);
    int g = cl >> 2;
    *(unsigned*)(T + dl * 256 + ((g ^ (dl & 15)) << 4) + (cl & 3) * 4) = u;
  }
  __syncthreads();
#pragma unroll
  for (int qq = 0; qq < 2; ++qq) {
    int gid = qq * 256 + tid;
    int dl = gid >> 4;
    int s = gid & 15;
    int d = d0 + dl;
    if (d >= dhi || d < dlo) continue;
    uint4 val = *(const uint4*)(T + dl * 256 + ((s ^ (dl & 15)) << 4));
    size_t dst = base + ((size_t)d << 11) + (size_t)((2 * by + (s >> 3)) << 7) +
                 (((s & 7) ^ (d & 7)) << 4);
    *(uint4*)(ws + dst) = val;
  }
}

// ---------- big levels (0..4): fp16 MFMA GEMM + fused gate ----------
// 192x256 tile, 256 threads, 4 waves = 2 rg x 2 cg; per-wave tile 96x128 (cf=8).
// Fatter wave tile cuts LDS-read bytes/col by 30% and makes MFMA the largest
// per-step term. BK=64 (16 steps). LDS = 2x24K (A) + 2x32K (B) = 112 KB.
// __launch_bounds__(256,1): full single-wave VGPR budget for the 192-reg acc.
__global__ __launch_bounds__(256, 1) void mfma_level_k(const float* __restrict__ bias,
                                                       const int* __restrict__ Nvec,
                                                       char* __restrict__ ws,
                                                       float* __restrict__ dout,
                                                       int level, int tiles) {
  __shared__ char smem[114688];  // A: 2 x 24576 @0, B: 2 x 32768 @49152
  const int id = blockIdx.x;
  const int o0 = (id & 7) * 64;   // o-group pinned to XCD via id%8 (W slice L2-resident)
  const int r2 = id >> 3;
  const int xb = r2 % tiles;
  const int b = r2 / tiles;
  if (b >= BATCH) return;

  size_t offC0, offA, offB; int n, nfp2, half;
  layout(Nvec, b, offC0, offA, offB, n, nfp2, half);

  int cols;
  size_t inOff, outOff;
  if (level == 0) {
    if (half == 0) return;
    cols = half;
    inOff = offC0;
    outOff = offA;
  } else {
    int w = nfp2 >> (level - 1);
    if (w < 2) return;
    cols = w >> 1;
    inOff = (level & 1) ? offA : offB;
    outOff = (level & 1) ? offB : offA;
  }
  const bool fin = (level > 0) && ((nfp2 >> level) == 1);
  const int l0 = xb * 256;
  if (l0 >= cols) return;

  const int tid = threadIdx.x;
  const int lane = tid & 63, wid = tid >> 6;
  const int lane15 = lane & 15, lq = lane >> 4;
  const int rg = wid & 1, cg = wid >> 1;   // cg in {0,1}, 128 cols each
  const char* inp = ws + inOff;

  unsigned aoff[6]; int adst[6];
#pragma unroll
  for (int q = 0; q < 6; ++q) {
    int d = q * 4096 + tid * 16;
    int r = d >> 7;                               // tile row 0..191
    int p = d & 127;                              // byte within 128-B row
    int o = ((r >> 6) << 9) + o0 + (r & 63);      // global output row
    aoff[q] = ((unsigned)o << 7) + p;
    adst[q] = q * 4096 + wid * 1024;
  }
  unsigned boff[8]; int bdst[8];
#pragma unroll
  for (int q = 0; q < 8; ++q) {
    int d = q * 4096 + tid * 16;
    int l = d >> 7;                               // col within tile 0..255
    int p = d & 127;
    int lc = l0 + l; if (lc > cols - 1) lc = cols - 1;
    boff[q] = ((unsigned)lc << 11) + p;
    bdst[q] = q * 4096 + wid * 1024;
  }

#define STAGE(st, sel) do {                                                  \
    char* Ab = smem + (sel) * 24576;                                         \
    char* Bb = smem + 49152 + (sel) * 32768;                                 \
    unsigned ka = (unsigned)(st) * 196608u;                                  \
    unsigned kb = (unsigned)(st) << 7;                                       \
    _Pragma("unroll") for (int q = 0; q < 6; ++q)                            \
      gload16(ws + ka + aoff[q], Ab + adst[q]);                              \
    _Pragma("unroll") for (int q = 0; q < 8; ++q)                            \
      gload16(inp + kb + boff[q], Bb + bdst[q]);                             \
  } while (0)

  f4v acc[6][8];
#pragma unroll
  for (int m = 0; m < 6; ++m)
#pragma unroll
    for (int cf = 0; cf < 8; ++cf) acc[m][cf] = (f4v){0.f, 0.f, 0.f, 0.f};

  STAGE(0, 0);
  __syncthreads();

#pragma unroll 1
  for (int st = 0; st < 16; ++st) {
    const int cur = st & 1;
    if (st + 1 < 16) STAGE(st + 1, cur ^ 1);  // prefetch overlaps this step's compute
    const char* Asb = smem + cur * 24576;
    const char* Bsb = smem + 49152 + cur * 32768;

#pragma unroll
    for (int s2 = 0; s2 < 2; ++s2) {
      const int oct = (s2 << 2) | lq;           // k-octant within the 64-k step
      h8v bh[8];
#pragma unroll
      for (int cf = 0; cf < 8; ++cf) {
        int ll = cg * 128 + cf * 16 + lane15;
        bh[cf] = *(const h8v*)(Bsb + ll * 128 + ((oct ^ (ll & 7)) << 4));
      }
#pragma unroll
      for (int m = 0; m < 6; ++m) {
        int rr = (m >> 1) * 64 + rg * 32 + (m & 1) * 16 + lane15;
        h8v ah = *(const h8v*)(Asb + rr * 128 + ((oct ^ (rr & 7)) << 4));
#pragma unroll
        for (int cf = 0; cf < 8; ++cf)
          acc[m][cf] = __builtin_amdgcn_mfma_f32_16x16x32_f16(ah, bh[cf], acc[m][cf], 0, 0, 0);
      }
    }
    __syncthreads();
  }
#undef STAGE

  // epilogue
  char* outp = ws + outOff;
#pragma unroll
  for (int s = 0; s < 2; ++s) {
#pragma unroll
    for (int cf = 0; cf < 8; ++cf) {
      f4v vl = acc[s][cf], vr = acc[2 + s][cf], vg = acc[4 + s][cf];
      int l = l0 + cg * 128 + cf * 16 + lane15;
      if (l >= cols) continue;
      int P = l >> 1, par = l & 1;
#pragma unroll
      for (int j = 0; j < 4; ++j) {
        int c = o0 + rg * 32 + s * 16 + lq * 4 + j;
        float zl = vl[j] + bias[c];
        float zr = vr[j] + bias[CH + c];
        float zg = vg[j] + bias[2 * CH + c];
        float g = 1.f / (1.f + __expf(-zg));
        float rt = 1.f - 2.f / (1.f + __expf(2.f * zr));
        float val = zl * g + rt * (1.f - g);
        if (fin) {
          if (l == 0) dout[(size_t)b * CH + c] = val;
        } else {
          int k = 2 * c + par;
          size_t byte = ((size_t)P << 11) + (size_t)((k >> 6) << 7) +
                        ((((k >> 3) & 7) ^ (P & 7)) << 4) + ((k & 7) << 1);
          *(unsigned short*)(outp + byte) = h2u((_Float16)val);
        }
      }
    }
  }
}

// ---------- small levels (5..12, cols <= 128): BK=128, 192x64 tile (r14, proven) ----------
__global__ __launch_bounds__(256, 2) void small_level_k(const float* __restrict__ bias,
                                                        const int* __restrict__ Nvec,
                                                        char* __restrict__ ws,
                                                        float* __restrict__ dout,
                                                        int level, int tiles) {
  __shared__ char smem[131072];  // A: 2 x 49152 @0, B: 2 x 16384 @98304
  const int id = blockIdx.x;
  const int o0 = (id & 7) * 64;
  const int r2 = id >> 3;
  const int xb = r2 % tiles;
  const int b = r2 / tiles;
  if (b >= BATCH) return;

  size_t offC0, offA, offB; int n, nfp2, half;
  layout(Nvec, b, offC0, offA, offB, n, nfp2, half);

  int w = nfp2 >> (level - 1);
  if (w < 2) return;
  const int cols = w >> 1;
  const size_t inOff = (level & 1) ? offA : offB;
  const size_t outOff = (level & 1) ? offB : offA;
  const bool fin = (cols == 1);
  const int l0 = xb * 64;
  if (l0 >= cols) return;

  const int tid = threadIdx.x;
  const int lane = tid & 63, wid = tid >> 6;
  const int lane15 = lane & 15, lq = lane >> 4;
  const int rg = wid & 1, cg = wid >> 1;
  const char* inp = ws + inOff;

  unsigned aoff[12]; int adst[12];
#pragma unroll
  for (int q = 0; q < 12; ++q) {
    int d = q * 4096 + tid * 16;
    int r = d >> 8;                               // tile row 0..191 (256 B rows)
    int p = d & 255;
    int o = ((r >> 6) << 9) + o0 + (r & 63);
    aoff[q] = (unsigned)(p >> 7) * 196608u + ((unsigned)o << 7) + (p & 127);
    adst[q] = q * 4096 + wid * 1024;
  }
  unsigned boff[4]; int bdst[4];
#pragma unroll
  for (int q = 0; q < 4; ++q) {
    int d = q * 4096 + tid * 16;
    int l = d >> 8;                               // col 0..63
    int p = d & 255;
    int lc = l0 + l; if (lc > cols - 1) lc = cols - 1;
    boff[q] = ((unsigned)lc << 11) + (unsigned)((p >> 7) << 7) + (p & 127);
    bdst[q] = q * 4096 + wid * 1024;
  }

#define STAGES(st, sel) do {                                                 \
    char* Ab = smem + (sel) * 49152;                                         \
    char* Bb = smem + 98304 + (sel) * 16384;                                 \
    unsigned ka = (unsigned)(st) * 393216u;                                  \
    unsigned kb = (unsigned)(st) << 8;                                       \
    _Pragma("unroll") for (int q = 0; q < 12; ++q)                           \
      gload16(ws + ka + aoff[q], Ab + adst[q]);                              \
    _Pragma("unroll") for (int q = 0; q < 4; ++q)                            \
      gload16(inp + kb + boff[q], Bb + bdst[q]);                             \
  } while (0)

  f4v acc[6][2];
#pragma unroll
  for (int m = 0; m < 6; ++m)
#pragma unroll
    for (int cf = 0; cf < 2; ++cf) acc[m][cf] = (f4v){0.f, 0.f, 0.f, 0.f};

  STAGES(0, 0);
  __syncthreads();

#pragma unroll 1
  for (int st = 0; st < 8; ++st) {
    const int cur = st & 1;
    if (st + 1 < 8) STAGES(st + 1, cur ^ 1);
    const char* Asb = smem + cur * 49152;
    const char* Bsb = smem + 98304 + cur * 16384;

#pragma unroll
    for (int sub = 0; sub < 2; ++sub) {
#pragma unroll
      for (int s2 = 0; s2 < 2; ++s2) {
        const int oct = (s2 << 2) | lq;
        h8v bh[2];
#pragma unroll
        for (int cf = 0; cf < 2; ++cf) {
          int ll = cg * 32 + cf * 16 + lane15;
          bh[cf] = *(const h8v*)(Bsb + ll * 256 + sub * 128 + ((oct ^ (ll & 7)) << 4));
        }
#pragma unroll
        for (int m = 0; m < 6; ++m) {
          int rr = (m >> 1) * 64 + rg * 32 + (m & 1) * 16 + lane15;
          h8v ah = *(const h8v*)(Asb + rr * 256 + sub * 128 + ((oct ^ (rr & 7)) << 4));
#pragma unroll
          for (int cf = 0; cf < 2; ++cf)
            acc[m][cf] = __builtin_amdgcn_mfma_f32_16x16x32_f16(ah, bh[cf], acc[m][cf], 0, 0, 0);
        }
      }
    }
    __syncthreads();
  }
#undef STAGES

  char* outp = ws + outOff;
#pragma unroll
  for (int s = 0; s < 2; ++s) {
#pragma unroll
    for (int cf = 0; cf < 2; ++cf) {
      f4v vl = acc[s][cf], vr = acc[2 + s][cf], vg = acc[4 + s][cf];
      int l = l0 + cg * 32 + cf * 16 + lane15;
      if (l >= cols) continue;
      int P = l >> 1, par = l & 1;
#pragma unroll
      for (int j = 0; j < 4; ++j) {
        int c = o0 + rg * 32 + s * 16 + lq * 4 + j;
        float zl = vl[j] + bias[c];
        float zr = vr[j] + bias[CH + c];
        float zg = vg[j] + bias[2 * CH + c];
        float g = 1.f / (1.f + __expf(-zg));
        float rt = 1.f - 2.f / (1.f + __expf(2.f * zr));
        float val = zl * g + rt * (1.f - g);
        if (fin) {
          if (l == 0) dout[(size_t)b * CH + c] = val;
        } else {
          int k = 2 * c + par;
          size_t byte = ((size_t)P << 11) + (size_t)((k >> 6) << 7) +
                        ((((k >> 3) & 7) ^ (P & 7)) << 4) + ((k & 7) << 1);
          *(unsigned short*)(outp + byte) = h2u((_Float16)val);
        }
      }
    }
  }
}

extern "C" void kernel_launch(void* const* d_in, const int* in_sizes, int n_in,
                              void* d_out, int out_size, void* d_ws, size_t ws_size,
                              hipStream_t stream) {
  const float* h = (const float*)d_in[0];
  const float* W = (const float*)d_in[1];
  const float* bias = (const float*)d_in[2];
  const int* Nvec = (const int*)d_in[3];
  float* dout = (float*)d_out;
  char* ws = (char*)d_ws;

  prep_w_k<<<dim3(96), 256, 0, stream>>>(W, ws);
  reorg_h_k<<<dim3(64, 8, BATCH), 256, 0, stream>>>(h, Nvec, ws, dout, 0);
  reorg_h_k<<<dim3(64, 8, BATCH), 256, 0, stream>>>(h, Nvec, ws, dout, 1);

  // level 0: max half = 952 -> 4 tiles of 256
  mfma_level_k<<<dim3(4 * 8 * BATCH), 256, 0, stream>>>(bias, Nvec, ws, dout, 0, 4);
  // big tree levels 1..4 (cols up to 2048), 256-col tiles
  for (int lev = 1; lev <= 4; ++lev) {
    int tiles = (LMAX >> lev) / 256; if (tiles < 1) tiles = 1;
    mfma_level_k<<<dim3(tiles * 8 * BATCH), 256, 0, stream>>>(bias, Nvec, ws, dout, lev, tiles);
  }
  // small tree levels 5..12 (cols <= 128): BK=128 kernel, 64-col tiles
  for (int lev = 5; lev <= 12; ++lev) {
    int colsmax = LMAX >> lev;
    int tiles = (colsmax + 63) / 64; if (tiles < 1) tiles = 1;
    small_level_k<<<dim3(tiles * 8 * BATCH), 256, 0, stream>>>(bias, Nvec, ws, dout, lev, tiles);
  }
}

// Round 19
// 511.776 us; speedup vs baseline: 1.0449x; 1.0026x over previous
//
#include <hip/hip_runtime.h>

#define BATCH 16
#define CH 512
#define OC 1536
#define KDIM 1024
#define LMAX 4096
#define WGLOB_SZ 3145728  // 16 steps * 1536 rows * 128 B (fp16, 64 k per step)

typedef __attribute__((ext_vector_type(8))) _Float16 h8v;
typedef __attribute__((ext_vector_type(4))) float f4v;

__device__ __forceinline__ int nfp2_of(int n) { return 1 << (31 - __clz(n)); }

__device__ __forceinline__ unsigned short h2u(_Float16 h) {
  union { _Float16 h; unsigned short u; } v; v.h = h; return v.u;
}

// per-batch arena layout; records are 2KB (1024 fp16)
// record: chunk = k>>6 (128 B), slot s in chunk holds k-octant (s ^ (d&7)), 8 fp16
__device__ __forceinline__ void layout(const int* __restrict__ Nvec, int b,
                                       size_t& offC0, size_t& offA, size_t& offB,
                                       int& n, int& nfp2, int& half) {
  size_t c0t = 0, at = 0, bt = 0, c0o = 0, ao = 0, bo = 0;
  n = 2; nfp2 = 2; half = 0;
#pragma unroll 1
  for (int i = 0; i < BATCH; ++i) {
    int ni = Nvec[i];
    int f = nfp2_of(ni);
    int hf = ni - f;
    size_t cs = (size_t)((hf + 127) & ~127) << 11;
    size_t as = (size_t)(f >> 1) << 11;
    size_t bs = (size_t)(f >> 2) << 11;
    if (i < b) { c0o += cs; ao += as; bo += bs; }
    if (i == b) { n = ni; nfp2 = f; half = hf; }
    c0t += cs; at += as; bt += bs;
  }
  offC0 = (size_t)WGLOB_SZ + c0o;
  offA = (size_t)WGLOB_SZ + c0t + ao;
  offB = (size_t)WGLOB_SZ + c0t + at + bo;
}

__device__ __forceinline__ void gload16(const void* g, void* l) {
  __builtin_amdgcn_global_load_lds((const __attribute__((address_space(1))) void*)g,
                                   (__attribute__((address_space(3))) void*)l, 16, 0, 0);
}

// ---------- W prep: W[o][k] fp32 -> Wglob[step][o][128 B], slot s = octant s^(o&7) ----------
__global__ __launch_bounds__(256) void prep_w_k(const float* __restrict__ W, char* __restrict__ ws) {
  int idx = blockIdx.x * 256 + threadIdx.x;  // idx = step*1536 + o
  if (idx >= 16 * 1536) return;
  int step = idx / 1536;
  int o = idx - step * 1536;
  const float* src = W + (size_t)o * KDIM + step * 64;
  unsigned short hb[64];
#pragma unroll
  for (int t = 0; t < 64; ++t) hb[t] = h2u((_Float16)src[t]);
  uint4* d4 = (uint4*)(ws + ((size_t)idx << 7));
#pragma unroll
  for (int s = 0; s < 8; ++s) {
    int oc = (s ^ (o & 7)) * 8;
    uint4 v;
    v.x = (unsigned)hb[oc + 0] | ((unsigned)hb[oc + 1] << 16);
    v.y = (unsigned)hb[oc + 2] | ((unsigned)hb[oc + 3] << 16);
    v.z = (unsigned)hb[oc + 4] | ((unsigned)hb[oc + 5] << 16);
    v.w = (unsigned)hb[oc + 6] | ((unsigned)hb[oc + 7] << 16);
    d4[s] = v;
  }
}

// ---------- h reorg: coalesced read + LDS transpose -> fp16 records ----------
__global__ __launch_bounds__(256) void reorg_h_k(const float* __restrict__ h,
                                                 const int* __restrict__ Nvec,
                                                 char* __restrict__ ws,
                                                 float* __restrict__ dout, int mode) {
  __shared__ char T[32 * 256];  // 8 KB
  const int b = blockIdx.z;
  size_t offC0, offA, offB; int n, nfp2, half;
  layout(Nvec, b, offC0, offA, offB, n, nfp2, half);
  const int tid = threadIdx.x;
  const int by = blockIdx.y;
  const int c0 = by * 64;

  if (mode == 1 && nfp2 == 1) {  // degenerate: answer is h[:, 0]
    if (blockIdx.x == 0 && tid < 64)
      dout[(size_t)b * CH + c0 + tid] = h[(size_t)b * CH * LMAX + (size_t)(c0 + tid) * LMAX];
    return;
  }

  const int d0 = blockIdx.x * 32;
  int dlo, dhi, soff;
  size_t base;
  if (mode == 0) { dlo = 0; dhi = half; soff = 0; base = offC0; }
  else { dlo = half >> 1; dhi = nfp2 >> 1; soff = half; base = offA; }
  if (d0 >= dhi || d0 + 32 <= dlo) return;

  const float* hb = h + (size_t)b * CH * LMAX;

#pragma unroll
  for (int q = 0; q < 8; ++q) {
    int id = q * 256 + tid;
    int cl = id >> 5;
    int dl = id & 31;
    int d = d0 + dl;
    bool ok = (d < dhi) && (d >= dlo);
    float2 v;
    v.x = 0.f; v.y = 0.f;
    if (ok) v = *(const float2*)(hb + (size_t)(c0 + cl) * LMAX + 2 * d + soff);
    unsigned u = (unsigned)h2u((_Float16)v.x) | ((unsigned)h2u((_Float16)v.y) << 16);
    int g = cl >> 2;
    *(unsigned*)(T + dl * 256 + ((g ^ (dl & 15)) << 4) + (cl & 3) * 4) = u;
  }
  __syncthreads();
#pragma unroll
  for (int qq = 0; qq < 2; ++qq) {
    int gid = qq * 256 + tid;
    int dl = gid >> 4;
    int s = gid & 15;
    int d = d0 + dl;
    if (d >= dhi || d < dlo) continue;
    uint4 val = *(const uint4*)(T + dl * 256 + ((s ^ (dl & 15)) << 4));
    size_t dst = base + ((size_t)d << 11) + (size_t)((2 * by + (s >> 3)) << 7) +
                 (((s & 7) ^ (d & 7)) << 4);
    *(uint4*)(ws + dst) = val;
  }
}

// ---------- big levels (0..4): fp16 MFMA GEMM + fused gate ----------
// 192x256 tile, 256 threads, 4 waves = 2 rg x 2 cg; per-wave tile 96x128 (cf=8).
// Fatter wave tile cuts LDS-read bytes/col by 30% and makes MFMA the largest
// per-step term. BK=64 (16 steps). LDS = 2x24K (A) + 2x32K (B) = 112 KB.
// __launch_bounds__(256,1): full single-wave VGPR budget for the 192-reg acc.
__global__ __launch_bounds__(256, 1) void mfma_level_k(const float* __restrict__ bias,
                                                       const int* __restrict__ Nvec,
                                                       char* __restrict__ ws,
                                                       float* __restrict__ dout,
                                                       int level, int tiles) {
  __shared__ char smem[114688];  // A: 2 x 24576 @0, B: 2 x 32768 @49152
  const int id = blockIdx.x;
  const int o0 = (id & 7) * 64;   // o-group pinned to XCD via id%8 (W slice L2-resident)
  const int r2 = id >> 3;
  const int xb = r2 % tiles;
  const int b = r2 / tiles;
  if (b >= BATCH) return;

  size_t offC0, offA, offB; int n, nfp2, half;
  layout(Nvec, b, offC0, offA, offB, n, nfp2, half);

  int cols;
  size_t inOff, outOff;
  if (level == 0) {
    if (half == 0) return;
    cols = half;
    inOff = offC0;
    outOff = offA;
  } else {
    int w = nfp2 >> (level - 1);
    if (w < 2) return;
    cols = w >> 1;
    inOff = (level & 1) ? offA : offB;
    outOff = (level & 1) ? offB : offA;
  }
  const bool fin = (level > 0) && ((nfp2 >> level) == 1);
  const int l0 = xb * 256;
  if (l0 >= cols) return;

  const int tid = threadIdx.x;
  const int lane = tid & 63, wid = tid >> 6;
  const int lane15 = lane & 15, lq = lane >> 4;
  const int rg = wid & 1, cg = wid >> 1;   // cg in {0,1}, 128 cols each
  const char* inp = ws + inOff;

  unsigned aoff[6]; int adst[6];
#pragma unroll
  for (int q = 0; q < 6; ++q) {
    int d = q * 4096 + tid * 16;
    int r = d >> 7;                               // tile row 0..191
    int p = d & 127;                              // byte within 128-B row
    int o = ((r >> 6) << 9) + o0 + (r & 63);      // global output row
    aoff[q] = ((unsigned)o << 7) + p;
    adst[q] = q * 4096 + wid * 1024;
  }
  unsigned boff[8]; int bdst[8];
#pragma unroll
  for (int q = 0; q < 8; ++q) {
    int d = q * 4096 + tid * 16;
    int l = d >> 7;                               // col within tile 0..255
    int p = d & 127;
    int lc = l0 + l; if (lc > cols - 1) lc = cols - 1;
    boff[q] = ((unsigned)lc << 11) + p;
    bdst[q] = q * 4096 + wid * 1024;
  }

#define STAGE(st, sel) do {                                                  \
    char* Ab = smem + (sel) * 24576;                                         \
    char* Bb = smem + 49152 + (sel) * 32768;                                 \
    unsigned ka = (unsigned)(st) * 196608u;                                  \
    unsigned kb = (unsigned)(st) << 7;                                       \
    _Pragma("unroll") for (int q = 0; q < 6; ++q)                            \
      gload16(ws + ka + aoff[q], Ab + adst[q]);                              \
    _Pragma("unroll") for (int q = 0; q < 8; ++q)                            \
      gload16(inp + kb + boff[q], Bb + bdst[q]);                             \
  } while (0)

  f4v acc[6][8];
#pragma unroll
  for (int m = 0; m < 6; ++m)
#pragma unroll
    for (int cf = 0; cf < 8; ++cf) acc[m][cf] = (f4v){0.f, 0.f, 0.f, 0.f};

  STAGE(0, 0);
  __syncthreads();

#pragma unroll 1
  for (int st = 0; st < 16; ++st) {
    const int cur = st & 1;
    if (st + 1 < 16) STAGE(st + 1, cur ^ 1);  // prefetch overlaps this step's compute
    const char* Asb = smem + cur * 24576;
    const char* Bsb = smem + 49152 + cur * 32768;

#pragma unroll
    for (int s2 = 0; s2 < 2; ++s2) {
      const int oct = (s2 << 2) | lq;           // k-octant within the 64-k step
      h8v bh[8];
#pragma unroll
      for (int cf = 0; cf < 8; ++cf) {
        int ll = cg * 128 + cf * 16 + lane15;
        bh[cf] = *(const h8v*)(Bsb + ll * 128 + ((oct ^ (ll & 7)) << 4));
      }
#pragma unroll
      for (int m = 0; m < 6; ++m) {
        int rr = (m >> 1) * 64 + rg * 32 + (m & 1) * 16 + lane15;
        h8v ah = *(const h8v*)(Asb + rr * 128 + ((oct ^ (rr & 7)) << 4));
#pragma unroll
        for (int cf = 0; cf < 8; ++cf)
          acc[m][cf] = __builtin_amdgcn_mfma_f32_16x16x32_f16(ah, bh[cf], acc[m][cf], 0, 0, 0);
      }
    }
    __syncthreads();
  }
#undef STAGE

  // epilogue
  char* outp = ws + outOff;
#pragma unroll
  for (int s = 0; s < 2; ++s) {
#pragma unroll
    for (int cf = 0; cf < 8; ++cf) {
      f4v vl = acc[s][cf], vr = acc[2 + s][cf], vg = acc[4 + s][cf];
      int l = l0 + cg * 128 + cf * 16 + lane15;
      if (l >= cols) continue;
      int P = l >> 1, par = l & 1;
#pragma unroll
      for (int j = 0; j < 4; ++j) {
        int c = o0 + rg * 32 + s * 16 + lq * 4 + j;
        float zl = vl[j] + bias[c];
        float zr = vr[j] + bias[CH + c];
        float zg = vg[j] + bias[2 * CH + c];
        float g = 1.f / (1.f + __expf(-zg));
        float rt = 1.f - 2.f / (1.f + __expf(2.f * zr));
        float val = zl * g + rt * (1.f - g);
        if (fin) {
          if (l == 0) dout[(size_t)b * CH + c] = val;
        } else {
          int k = 2 * c + par;
          size_t byte = ((size_t)P << 11) + (size_t)((k >> 6) << 7) +
                        ((((k >> 3) & 7) ^ (P & 7)) << 4) + ((k & 7) << 1);
          *(unsigned short*)(outp + byte) = h2u((_Float16)val);
        }
      }
    }
  }
}

// ---------- small levels (5..12, cols <= 128): BK=128, 192x64 tile (r14, proven) ----------
__global__ __launch_bounds__(256, 2) void small_level_k(const float* __restrict__ bias,
                                                        const int* __restrict__ Nvec,
                                                        char* __restrict__ ws,
                                                        float* __restrict__ dout,
                                                        int level, int tiles) {
  __shared__ char smem[131072];  // A: 2 x 49152 @0, B: 2 x 16384 @98304
  const int id = blockIdx.x;
  const int o0 = (id & 7) * 64;
  const int r2 = id >> 3;
  const int xb = r2 % tiles;
  const int b = r2 / tiles;
  if (b >= BATCH) return;

  size_t offC0, offA, offB; int n, nfp2, half;
  layout(Nvec, b, offC0, offA, offB, n, nfp2, half);

  int w = nfp2 >> (level - 1);
  if (w < 2) return;
  const int cols = w >> 1;
  const size_t inOff = (level & 1) ? offA : offB;
  const size_t outOff = (level & 1) ? offB : offA;
  const bool fin = (cols == 1);
  const int l0 = xb * 64;
  if (l0 >= cols) return;

  const int tid = threadIdx.x;
  const int lane = tid & 63, wid = tid >> 6;
  const int lane15 = lane & 15, lq = lane >> 4;
  const int rg = wid & 1, cg = wid >> 1;
  const char* inp = ws + inOff;

  unsigned aoff[12]; int adst[12];
#pragma unroll
  for (int q = 0; q < 12; ++q) {
    int d = q * 4096 + tid * 16;
    int r = d >> 8;                               // tile row 0..191 (256 B rows)
    int p = d & 255;
    int o = ((r >> 6) << 9) + o0 + (r & 63);
    aoff[q] = (unsigned)(p >> 7) * 196608u + ((unsigned)o << 7) + (p & 127);
    adst[q] = q * 4096 + wid * 1024;
  }
  unsigned boff[4]; int bdst[4];
#pragma unroll
  for (int q = 0; q < 4; ++q) {
    int d = q * 4096 + tid * 16;
    int l = d >> 8;                               // col 0..63
    int p = d & 255;
    int lc = l0 + l; if (lc > cols - 1) lc = cols - 1;
    boff[q] = ((unsigned)lc << 11) + (unsigned)((p >> 7) << 7) + (p & 127);
    bdst[q] = q * 4096 + wid * 1024;
  }

#define STAGES(st, sel) do {                                                 \
    char* Ab = smem + (sel) * 49152;                                         \
    char* Bb = smem + 98304 + (sel) * 16384;                                 \
    unsigned ka = (unsigned)(st) * 393216u;                                  \
    unsigned kb = (unsigned)(st) << 8;                                       \
    _Pragma("unroll") for (int q = 0; q < 12; ++q)                           \
      gload16(ws + ka + aoff[q], Ab + adst[q]);                              \
    _Pragma("unroll") for (int q = 0; q < 4; ++q)                            \
      gload16(inp + kb + boff[q], Bb + bdst[q]);                             \
  } while (0)

  f4v acc[6][2];
#pragma unroll
  for (int m = 0; m < 6; ++m)
#pragma unroll
    for (int cf = 0; cf < 2; ++cf) acc[m][cf] = (f4v){0.f, 0.f, 0.f, 0.f};

  STAGES(0, 0);
  __syncthreads();

#pragma unroll 1
  for (int st = 0; st < 8; ++st) {
    const int cur = st & 1;
    if (st + 1 < 8) STAGES(st + 1, cur ^ 1);
    const char* Asb = smem + cur * 49152;
    const char* Bsb = smem + 98304 + cur * 16384;

#pragma unroll
    for (int sub = 0; sub < 2; ++sub) {
#pragma unroll
      for (int s2 = 0; s2 < 2; ++s2) {
        const int oct = (s2 << 2) | lq;
        h8v bh[2];
#pragma unroll
        for (int cf = 0; cf < 2; ++cf) {
          int ll = cg * 32 + cf * 16 + lane15;
          bh[cf] = *(const h8v*)(Bsb + ll * 256 + sub * 128 + ((oct ^ (ll & 7)) << 4));
        }
#pragma unroll
        for (int m = 0; m < 6; ++m) {
          int rr = (m >> 1) * 64 + rg * 32 + (m & 1) * 16 + lane15;
          h8v ah = *(const h8v*)(Asb + rr * 256 + sub * 128 + ((oct ^ (rr & 7)) << 4));
#pragma unroll
          for (int cf = 0; cf < 2; ++cf)
            acc[m][cf] = __builtin_amdgcn_mfma_f32_16x16x32_f16(ah, bh[cf], acc[m][cf], 0, 0, 0);
        }
      }
    }
    __syncthreads();
  }
#undef STAGES

  char* outp = ws + outOff;
#pragma unroll
  for (int s = 0; s < 2; ++s) {
#pragma unroll
    for (int cf = 0; cf < 2; ++cf) {
      f4v vl = acc[s][cf], vr = acc[2 + s][cf], vg = acc[4 + s][cf];
      int l = l0 + cg * 32 + cf * 16 + lane15;
      if (l >= cols) continue;
      int P = l >> 1, par = l & 1;
#pragma unroll
      for (int j = 0; j < 4; ++j) {
        int c = o0 + rg * 32 + s * 16 + lq * 4 + j;
        float zl = vl[j] + bias[c];
        float zr = vr[j] + bias[CH + c];
        float zg = vg[j] + bias[2 * CH + c];
        float g = 1.f / (1.f + __expf(-zg));
        float rt = 1.f - 2.f / (1.f + __expf(2.f * zr));
        float val = zl * g + rt * (1.f - g);
        if (fin) {
          if (l == 0) dout[(size_t)b * CH + c] = val;
        } else {
          int k = 2 * c + par;
          size_t byte = ((size_t)P << 11) + (size_t)((k >> 6) << 7) +
                        ((((k >> 3) & 7) ^ (P & 7)) << 4) + ((k & 7) << 1);
          *(unsigned short*)(outp + byte) = h2u((_Float16)val);
        }
      }
    }
  }
}

extern "C" void kernel_launch(void* const* d_in, const int* in_sizes, int n_in,
                              void* d_out, int out_size, void* d_ws, size_t ws_size,
                              hipStream_t stream) {
  const float* h = (const float*)d_in[0];
  const float* W = (const float*)d_in[1];
  const float* bias = (const float*)d_in[2];
  const int* Nvec = (const int*)d_in[3];
  float* dout = (float*)d_out;
  char* ws = (char*)d_ws;

  prep_w_k<<<dim3(96), 256, 0, stream>>>(W, ws);
  reorg_h_k<<<dim3(64, 8, BATCH), 256, 0, stream>>>(h, Nvec, ws, dout, 0);
  reorg_h_k<<<dim3(64, 8, BATCH), 256, 0, stream>>>(h, Nvec, ws, dout, 1);

  // level 0: max half = 952 -> 4 tiles of 256
  mfma_level_k<<<dim3(4 * 8 * BATCH), 256, 0, stream>>>(bias, Nvec, ws, dout, 0, 4);
  // big tree levels 1..4 (cols up to 2048), 256-col tiles
  for (int lev = 1; lev <= 4; ++lev) {
    int tiles = (LMAX >> lev) / 256; if (tiles < 1) tiles = 1;
    mfma_level_k<<<dim3(tiles * 8 * BATCH), 256, 0, stream>>>(bias, Nvec, ws, dout, lev, tiles);
  }
  // small tree levels 5..12 (cols <= 128): BK=128 kernel, 64-col tiles
  for (int lev = 5; lev <= 12; ++lev) {
    int colsmax = LMAX >> lev;
    int tiles = (colsmax + 63) / 64; if (tiles < 1) tiles = 1;
    small_level_k<<<dim3(tiles * 8 * BATCH), 256, 0, stream>>>(bias, Nvec, ws, dout, lev, tiles);
  }
}

// Round 20
// 510.795 us; speedup vs baseline: 1.0469x; 1.0019x over previous
//
#include <hip/hip_runtime.h>

#define BATCH 16
#define CH 512
#define OC 1536
#define KDIM 1024
#define LMAX 4096
#define WGLOB_SZ 3145728  // 16 steps * 1536 rows * 128 B (fp16, 64 k per step)

typedef __attribute__((ext_vector_type(8))) _Float16 h8v;
typedef __attribute__((ext_vector_type(4))) float f4v;

__device__ __forceinline__ int nfp2_of(int n) { return 1 << (31 - __clz(n)); }

__device__ __forceinline__ unsigned short h2u(_Float16 h) {
  union { _Float16 h; unsigned short u; } v; v.h = h; return v.u;
}

// per-batch arena layout; records are 2KB (1024 fp16)
// record: chunk = k>>6 (128 B), slot s in chunk holds k-octant (s ^ (d&7)), 8 fp16
__device__ __forceinline__ void layout(const int* __restrict__ Nvec, int b,
                                       size_t& offC0, size_t& offA, size_t& offB,
                                       int& n, int& nfp2, int& half) {
  size_t c0t = 0, at = 0, bt = 0, c0o = 0, ao = 0, bo = 0;
  n = 2; nfp2 = 2; half = 0;
#pragma unroll 1
  for (int i = 0; i < BATCH; ++i) {
    int ni = Nvec[i];
    int f = nfp2_of(ni);
    int hf = ni - f;
    size_t cs = (size_t)((hf + 127) & ~127) << 11;
    size_t as = (size_t)(f >> 1) << 11;
    size_t bs = (size_t)(f >> 2) << 11;
    if (i < b) { c0o += cs; ao += as; bo += bs; }
    if (i == b) { n = ni; nfp2 = f; half = hf; }
    c0t += cs; at += as; bt += bs;
  }
  offC0 = (size_t)WGLOB_SZ + c0o;
  offA = (size_t)WGLOB_SZ + c0t + ao;
  offB = (size_t)WGLOB_SZ + c0t + at + bo;
}

__device__ __forceinline__ void gload16(const void* g, void* l) {
  __builtin_amdgcn_global_load_lds((const __attribute__((address_space(1))) void*)g,
                                   (__attribute__((address_space(3))) void*)l, 16, 0, 0);
}

// ---------- W prep: W[o][k] fp32 -> Wglob[step][o][128 B], slot s = octant s^(o&7) ----------
__global__ __launch_bounds__(256) void prep_w_k(const float* __restrict__ W, char* __restrict__ ws) {
  int idx = blockIdx.x * 256 + threadIdx.x;  // idx = step*1536 + o
  if (idx >= 16 * 1536) return;
  int step = idx / 1536;
  int o = idx - step * 1536;
  const float* src = W + (size_t)o * KDIM + step * 64;
  unsigned short hb[64];
#pragma unroll
  for (int t = 0; t < 64; ++t) hb[t] = h2u((_Float16)src[t]);
  uint4* d4 = (uint4*)(ws + ((size_t)idx << 7));
#pragma unroll
  for (int s = 0; s < 8; ++s) {
    int oc = (s ^ (o & 7)) * 8;
    uint4 v;
    v.x = (unsigned)hb[oc + 0] | ((unsigned)hb[oc + 1] << 16);
    v.y = (unsigned)hb[oc + 2] | ((unsigned)hb[oc + 3] << 16);
    v.z = (unsigned)hb[oc + 4] | ((unsigned)hb[oc + 5] << 16);
    v.w = (unsigned)hb[oc + 6] | ((unsigned)hb[oc + 7] << 16);
    d4[s] = v;
  }
}

// ---------- h reorg: coalesced read + LDS transpose -> fp16 records ----------
__global__ __launch_bounds__(256) void reorg_h_k(const float* __restrict__ h,
                                                 const int* __restrict__ Nvec,
                                                 char* __restrict__ ws,
                                                 float* __restrict__ dout, int mode) {
  __shared__ char T[32 * 256];  // 8 KB
  const int b = blockIdx.z;
  size_t offC0, offA, offB; int n, nfp2, half;
  layout(Nvec, b, offC0, offA, offB, n, nfp2, half);
  const int tid = threadIdx.x;
  const int by = blockIdx.y;
  const int c0 = by * 64;

  if (mode == 1 && nfp2 == 1) {  // degenerate: answer is h[:, 0]
    if (blockIdx.x == 0 && tid < 64)
      dout[(size_t)b * CH + c0 + tid] = h[(size_t)b * CH * LMAX + (size_t)(c0 + tid) * LMAX];
    return;
  }

  const int d0 = blockIdx.x * 32;
  int dlo, dhi, soff;
  size_t base;
  if (mode == 0) { dlo = 0; dhi = half; soff = 0; base = offC0; }
  else { dlo = half >> 1; dhi = nfp2 >> 1; soff = half; base = offA; }
  if (d0 >= dhi || d0 + 32 <= dlo) return;

  const float* hb = h + (size_t)b * CH * LMAX;

#pragma unroll
  for (int q = 0; q < 8; ++q) {
    int id = q * 256 + tid;
    int cl = id >> 5;
    int dl = id & 31;
    int d = d0 + dl;
    bool ok = (d < dhi) && (d >= dlo);
    float2 v;
    v.x = 0.f; v.y = 0.f;
    if (ok) v = *(const float2*)(hb + (size_t)(c0 + cl) * LMAX + 2 * d + soff);
    unsigned u = (unsigned)h2u((_Float16)v.x) | ((unsigned)h2u((_Float16)v.y) << 16);
    int g = cl >> 2;
    *(unsigned*)(T + dl * 256 + ((g ^ (dl & 15)) << 4) + (cl & 3) * 4) = u;
  }
  __syncthreads();
#pragma unroll
  for (int qq = 0; qq < 2; ++qq) {
    int gid = qq * 256 + tid;
    int dl = gid >> 4;
    int s = gid & 15;
    int d = d0 + dl;
    if (d >= dhi || d < dlo) continue;
    uint4 val = *(const uint4*)(T + dl * 256 + ((s ^ (dl & 15)) << 4));
    size_t dst = base + ((size_t)d << 11) + (size_t)((2 * by + (s >> 3)) << 7) +
                 (((s & 7) ^ (d & 7)) << 4);
    *(uint4*)(ws + dst) = val;
  }
}

// ---------- big levels (0..4): fp16 MFMA GEMM + fused gate ----------
// 192x256 tile, 256 threads, 4 waves = 2 rg x 2 cg; per-wave tile 96x128 (cf=8).
// Fatter wave tile cuts LDS-read bytes/col by 30% and makes MFMA the largest
// per-step term. BK=64 (16 steps). LDS = 2x24K (A) + 2x32K (B) = 112 KB.
// __launch_bounds__(256,1): full single-wave VGPR budget for the 192-reg acc.
__global__ __launch_bounds__(256, 1) void mfma_level_k(const float* __restrict__ bias,
                                                       const int* __restrict__ Nvec,
                                                       char* __restrict__ ws,
                                                       float* __restrict__ dout,
                                                       int level, int tiles) {
  __shared__ char smem[114688];  // A: 2 x 24576 @0, B: 2 x 32768 @49152
  const int id = blockIdx.x;
  const int o0 = (id & 7) * 64;   // o-group pinned to XCD via id%8 (W slice L2-resident)
  const int r2 = id >> 3;
  const int xb = r2 % tiles;
  const int b = r2 / tiles;
  if (b >= BATCH) return;

  size_t offC0, offA, offB; int n, nfp2, half;
  layout(Nvec, b, offC0, offA, offB, n, nfp2, half);

  int cols;
  size_t inOff, outOff;
  if (level == 0) {
    if (half == 0) return;
    cols = half;
    inOff = offC0;
    outOff = offA;
  } else {
    int w = nfp2 >> (level - 1);
    if (w < 2) return;
    cols = w >> 1;
    inOff = (level & 1) ? offA : offB;
    outOff = (level & 1) ? offB : offA;
  }
  const bool fin = (level > 0) && ((nfp2 >> level) == 1);
  const int l0 = xb * 256;
  if (l0 >= cols) return;

  const int tid = threadIdx.x;
  const int lane = tid & 63, wid = tid >> 6;
  const int lane15 = lane & 15, lq = lane >> 4;
  const int rg = wid & 1, cg = wid >> 1;   // cg in {0,1}, 128 cols each
  const char* inp = ws + inOff;

  unsigned aoff[6]; int adst[6];
#pragma unroll
  for (int q = 0; q < 6; ++q) {
    int d = q * 4096 + tid * 16;
    int r = d >> 7;                               // tile row 0..191
    int p = d & 127;                              // byte within 128-B row
    int o = ((r >> 6) << 9) + o0 + (r & 63);      // global output row
    aoff[q] = ((unsigned)o << 7) + p;
    adst[q] = q * 4096 + wid * 1024;
  }
  unsigned boff[8]; int bdst[8];
#pragma unroll
  for (int q = 0; q < 8; ++q) {
    int d = q * 4096 + tid * 16;
    int l = d >> 7;                               // col within tile 0..255
    int p = d & 127;
    int lc = l0 + l; if (lc > cols - 1) lc = cols - 1;
    boff[q] = ((unsigned)lc << 11) + p;
    bdst[q] = q * 4096 + wid * 1024;
  }

#define STAGE(st, sel) do {                                                  \
    char* Ab = smem + (sel) * 24576;                                         \
    char* Bb = smem + 49152 + (sel) * 32768;                                 \
    unsigned ka = (unsigned)(st) * 196608u;                                  \
    unsigned kb = (unsigned)(st) << 7;                                       \
    _Pragma("unroll") for (int q = 0; q < 6; ++q)                            \
      gload16(ws + ka + aoff[q], Ab + adst[q]);                              \
    _Pragma("unroll") for (int q = 0; q < 8; ++q)                            \
      gload16(inp + kb + boff[q], Bb + bdst[q]);                             \
  } while (0)

  f4v acc[6][8];
#pragma unroll
  for (int m = 0; m < 6; ++m)
#pragma unroll
    for (int cf = 0; cf < 8; ++cf) acc[m][cf] = (f4v){0.f, 0.f, 0.f, 0.f};

  STAGE(0, 0);
  __syncthreads();

#pragma unroll 1
  for (int st = 0; st < 16; ++st) {
    const int cur = st & 1;
    if (st + 1 < 16) STAGE(st + 1, cur ^ 1);  // prefetch overlaps this step's compute
    const char* Asb = smem + cur * 24576;
    const char* Bsb = smem + 49152 + cur * 32768;

#pragma unroll
    for (int s2 = 0; s2 < 2; ++s2) {
      const int oct = (s2 << 2) | lq;           // k-octant within the 64-k step
      h8v bh[8];
#pragma unroll
      for (int cf = 0; cf < 8; ++cf) {
        int ll = cg * 128 + cf * 16 + lane15;
        bh[cf] = *(const h8v*)(Bsb + ll * 128 + ((oct ^ (ll & 7)) << 4));
      }
#pragma unroll
      for (int m = 0; m < 6; ++m) {
        int rr = (m >> 1) * 64 + rg * 32 + (m & 1) * 16 + lane15;
        h8v ah = *(const h8v*)(Asb + rr * 128 + ((oct ^ (rr & 7)) << 4));
#pragma unroll
        for (int cf = 0; cf < 8; ++cf)
          acc[m][cf] = __builtin_amdgcn_mfma_f32_16x16x32_f16(ah, bh[cf], acc[m][cf], 0, 0, 0);
      }
    }
    __syncthreads();
  }
#undef STAGE

  // epilogue
  char* outp = ws + outOff;
#pragma unroll
  for (int s = 0; s < 2; ++s) {
#pragma unroll
    for (int cf = 0; cf < 8; ++cf) {
      f4v vl = acc[s][cf], vr = acc[2 + s][cf], vg = acc[4 + s][cf];
      int l = l0 + cg * 128 + cf * 16 + lane15;
      if (l >= cols) continue;
      int P = l >> 1, par = l & 1;
#pragma unroll
      for (int j = 0; j < 4; ++j) {
        int c = o0 + rg * 32 + s * 16 + lq * 4 + j;
        float zl = vl[j] + bias[c];
        float zr = vr[j] + bias[CH + c];
        float zg = vg[j] + bias[2 * CH + c];
        float g = 1.f / (1.f + __expf(-zg));
        float rt = 1.f - 2.f / (1.f + __expf(2.f * zr));
        float val = zl * g + rt * (1.f - g);
        if (fin) {
          if (l == 0) dout[(size_t)b * CH + c] = val;
        } else {
          int k = 2 * c + par;
          size_t byte = ((size_t)P << 11) + (size_t)((k >> 6) << 7) +
                        ((((k >> 3) & 7) ^ (P & 7)) << 4) + ((k & 7) << 1);
          *(unsigned short*)(outp + byte) = h2u((_Float16)val);
        }
      }
    }
  }
}

// ---------- small levels (5..12, cols <= 128): BK=128, 192x64 tile (r14, proven) ----------
__global__ __launch_bounds__(256, 2) void small_level_k(const float* __restrict__ bias,
                                                        const int* __restrict__ Nvec,
                                                        char* __restrict__ ws,
                                                        float* __restrict__ dout,
                                                        int level, int tiles) {
  __shared__ char smem[131072];  // A: 2 x 49152 @0, B: 2 x 16384 @98304
  const int id = blockIdx.x;
  const int o0 = (id & 7) * 64;
  const int r2 = id >> 3;
  const int xb = r2 % tiles;
  const int b = r2 / tiles;
  if (b >= BATCH) return;

  size_t offC0, offA, offB; int n, nfp2, half;
  layout(Nvec, b, offC0, offA, offB, n, nfp2, half);

  int w = nfp2 >> (level - 1);
  if (w < 2) return;
  const int cols = w >> 1;
  const size_t inOff = (level & 1) ? offA : offB;
  const size_t outOff = (level & 1) ? offB : offA;
  const bool fin = (cols == 1);
  const int l0 = xb * 64;
  if (l0 >= cols) return;

  const int tid = threadIdx.x;
  const int lane = tid & 63, wid = tid >> 6;
  const int lane15 = lane & 15, lq = lane >> 4;
  const int rg = wid & 1, cg = wid >> 1;
  const char* inp = ws + inOff;

  unsigned aoff[12]; int adst[12];
#pragma unroll
  for (int q = 0; q < 12; ++q) {
    int d = q * 4096 + tid * 16;
    int r = d >> 8;                               // tile row 0..191 (256 B rows)
    int p = d & 255;
    int o = ((r >> 6) << 9) + o0 + (r & 63);
    aoff[q] = (unsigned)(p >> 7) * 196608u + ((unsigned)o << 7) + (p & 127);
    adst[q] = q * 4096 + wid * 1024;
  }
  unsigned boff[4]; int bdst[4];
#pragma unroll
  for (int q = 0; q < 4; ++q) {
    int d = q * 4096 + tid * 16;
    int l = d >> 8;                               // col 0..63
    int p = d & 255;
    int lc = l0 + l; if (lc > cols - 1) lc = cols - 1;
    boff[q] = ((unsigned)lc << 11) + (unsigned)((p >> 7) << 7) + (p & 127);
    bdst[q] = q * 4096 + wid * 1024;
  }

#define STAGES(st, sel) do {                                                 \
    char* Ab = smem + (sel) * 49152;                                         \
    char* Bb = smem + 98304 + (sel) * 16384;                                 \
    unsigned ka = (unsigned)(st) * 393216u;                                  \
    unsigned kb = (unsigned)(st) << 8;                                       \
    _Pragma("unroll") for (int q = 0; q < 12; ++q)                           \
      gload16(ws + ka + aoff[q], Ab + adst[q]);                              \
    _Pragma("unroll") for (int q = 0; q < 4; ++q)                            \
      gload16(inp + kb + boff[q], Bb + bdst[q]);                             \
  } while (0)

  f4v acc[6][2];
#pragma unroll
  for (int m = 0; m < 6; ++m)
#pragma unroll
    for (int cf = 0; cf < 2; ++cf) acc[m][cf] = (f4v){0.f, 0.f, 0.f, 0.f};

  STAGES(0, 0);
  __syncthreads();

#pragma unroll 1
  for (int st = 0; st < 8; ++st) {
    const int cur = st & 1;
    if (st + 1 < 8) STAGES(st + 1, cur ^ 1);
    const char* Asb = smem + cur * 49152;
    const char* Bsb = smem + 98304 + cur * 16384;

#pragma unroll
    for (int sub = 0; sub < 2; ++sub) {
#pragma unroll
      for (int s2 = 0; s2 < 2; ++s2) {
        const int oct = (s2 << 2) | lq;
        h8v bh[2];
#pragma unroll
        for (int cf = 0; cf < 2; ++cf) {
          int ll = cg * 32 + cf * 16 + lane15;
          bh[cf] = *(const h8v*)(Bsb + ll * 256 + sub * 128 + ((oct ^ (ll & 7)) << 4));
        }
#pragma unroll
        for (int m = 0; m < 6; ++m) {
          int rr = (m >> 1) * 64 + rg * 32 + (m & 1) * 16 + lane15;
          h8v ah = *(const h8v*)(Asb + rr * 256 + sub * 128 + ((oct ^ (rr & 7)) << 4));
#pragma unroll
          for (int cf = 0; cf < 2; ++cf)
            acc[m][cf] = __builtin_amdgcn_mfma_f32_16x16x32_f16(ah, bh[cf], acc[m][cf], 0, 0, 0);
        }
      }
    }
    __syncthreads();
  }
#undef STAGES

  char* outp = ws + outOff;
#pragma unroll
  for (int s = 0; s < 2; ++s) {
#pragma unroll
    for (int cf = 0; cf < 2; ++cf) {
      f4v vl = acc[s][cf], vr = acc[2 + s][cf], vg = acc[4 + s][cf];
      int l = l0 + cg * 32 + cf * 16 + lane15;
      if (l >= cols) continue;
      int P = l >> 1, par = l & 1;
#pragma unroll
      for (int j = 0; j < 4; ++j) {
        int c = o0 + rg * 32 + s * 16 + lq * 4 + j;
        float zl = vl[j] + bias[c];
        float zr = vr[j] + bias[CH + c];
        float zg = vg[j] + bias[2 * CH + c];
        float g = 1.f / (1.f + __expf(-zg));
        float rt = 1.f - 2.f / (1.f + __expf(2.f * zr));
        float val = zl * g + rt * (1.f - g);
        if (fin) {
          if (l == 0) dout[(size_t)b * CH + c] = val;
        } else {
          int k = 2 * c + par;
          size_t byte = ((size_t)P << 11) + (size_t)((k >> 6) << 7) +
                        ((((k >> 3) & 7) ^ (P & 7)) << 4) + ((k & 7) << 1);
          *(unsigned short*)(outp + byte) = h2u((_Float16)val);
        }
      }
    }
  }
}

extern "C" void kernel_launch(void* const* d_in, const int* in_sizes, int n_in,
                              void* d_out, int out_size, void* d_ws, size_t ws_size,
                              hipStream_t stream) {
  const float* h = (const float*)d_in[0];
  const float* W = (const float*)d_in[1];
  const float* bias = (const float*)d_in[2];
  const int* Nvec = (const int*)d_in[3];
  float* dout = (float*)d_out;
  char* ws = (char*)d_ws;

  prep_w_k<<<dim3(96), 256, 0, stream>>>(W, ws);
  reorg_h_k<<<dim3(64, 8, BATCH), 256, 0, stream>>>(h, Nvec, ws, dout, 0);
  reorg_h_k<<<dim3(64, 8, BATCH), 256, 0, stream>>>(h, Nvec, ws, dout, 1);

  // level 0: max half = 952 -> 4 tiles of 256
  mfma_level_k<<<dim3(4 * 8 * BATCH), 256, 0, stream>>>(bias, Nvec, ws, dout, 0, 4);
  // big tree levels 1..4 (cols up to 2048), 256-col tiles
  for (int lev = 1; lev <= 4; ++lev) {
    int tiles = (LMAX >> lev) / 256; if (tiles < 1) tiles = 1;
    mfma_level_k<<<dim3(tiles * 8 * BATCH), 256, 0, stream>>>(bias, Nvec, ws, dout, lev, tiles);
  }
  // small tree levels 5..12 (cols <= 128): BK=128 kernel, 64-col tiles
  for (int lev = 5; lev <= 12; ++lev) {
    int colsmax = LMAX >> lev;
    int tiles = (colsmax + 63) / 64; if (tiles < 1) tiles = 1;
    small_level_k<<<dim3(tiles * 8 * BATCH), 256, 0, stream>>>(bias, Nvec, ws, dout, lev, tiles);
  }
}

// Round 21
// 457.262 us; speedup vs baseline: 1.1695x; 1.1171x over previous
//
#include <hip/hip_runtime.h>

#define BATCH 16
#define CH 512
#define OC 1536
#define KDIM 1024
#define LMAX 4096
#define WGLOB_SZ 3145728  // 16 steps * 1536 rows * 128 B (fp16, 64 k per step)

typedef __attribute__((ext_vector_type(8))) _Float16 h8v;
typedef __attribute__((ext_vector_type(4))) float f4v;

__device__ __forceinline__ int nfp2_of(int n) { return 1 << (31 - __clz(n)); }

__device__ __forceinline__ unsigned short h2u(_Float16 h) {
  union { _Float16 h; unsigned short u; } v; v.h = h; return v.u;
}

// per-batch arena layout; records are 2KB (1024 fp16)
// record: chunk = k>>6 (128 B), slot s in chunk holds k-octant (s ^ (d&7)), 8 fp16
__device__ __forceinline__ void layout(const int* __restrict__ Nvec, int b,
                                       size_t& offC0, size_t& offA, size_t& offB,
                                       int& n, int& nfp2, int& half) {
  size_t c0t = 0, at = 0, bt = 0, c0o = 0, ao = 0, bo = 0;
  n = 2; nfp2 = 2; half = 0;
#pragma unroll 1
  for (int i = 0; i < BATCH; ++i) {
    int ni = Nvec[i];
    int f = nfp2_of(ni);
    int hf = ni - f;
    size_t cs = (size_t)((hf + 127) & ~127) << 11;
    size_t as = (size_t)(f >> 1) << 11;
    size_t bs = (size_t)(f >> 2) << 11;
    if (i < b) { c0o += cs; ao += as; bo += bs; }
    if (i == b) { n = ni; nfp2 = f; half = hf; }
    c0t += cs; at += as; bt += bs;
  }
  offC0 = (size_t)WGLOB_SZ + c0o;
  offA = (size_t)WGLOB_SZ + c0t + ao;
  offB = (size_t)WGLOB_SZ + c0t + at + bo;
}

__device__ __forceinline__ void gload16(const void* g, void* l) {
  __builtin_amdgcn_global_load_lds((const __attribute__((address_space(1))) void*)g,
                                   (__attribute__((address_space(3))) void*)l, 16, 0, 0);
}

// ---------- W prep: W[o][k] fp32 -> Wglob[step][o][128 B], slot s = octant s^(o&7) ----------
__global__ __launch_bounds__(256) void prep_w_k(const float* __restrict__ W, char* __restrict__ ws) {
  int idx = blockIdx.x * 256 + threadIdx.x;  // idx = step*1536 + o
  if (idx >= 16 * 1536) return;
  int step = idx / 1536;
  int o = idx - step * 1536;
  const float* src = W + (size_t)o * KDIM + step * 64;
  unsigned short hb[64];
#pragma unroll
  for (int t = 0; t < 64; ++t) hb[t] = h2u((_Float16)src[t]);
  uint4* d4 = (uint4*)(ws + ((size_t)idx << 7));
#pragma unroll
  for (int s = 0; s < 8; ++s) {
    int oc = (s ^ (o & 7)) * 8;
    uint4 v;
    v.x = (unsigned)hb[oc + 0] | ((unsigned)hb[oc + 1] << 16);
    v.y = (unsigned)hb[oc + 2] | ((unsigned)hb[oc + 3] << 16);
    v.z = (unsigned)hb[oc + 4] | ((unsigned)hb[oc + 5] << 16);
    v.w = (unsigned)hb[oc + 6] | ((unsigned)hb[oc + 7] << 16);
    d4[s] = v;
  }
}

// ---------- h reorg: coalesced read + LDS transpose -> fp16 records ----------
// blockIdx.x in [0,128): mode = x>>6 (0: conv pairs -> C0, 1: suffix -> bufA)
__global__ __launch_bounds__(256) void reorg_h_k(const float* __restrict__ h,
                                                 const int* __restrict__ Nvec,
                                                 char* __restrict__ ws,
                                                 float* __restrict__ dout) {
  __shared__ char T[32 * 256];  // 8 KB
  const int b = blockIdx.z;
  size_t offC0, offA, offB; int n, nfp2, half;
  layout(Nvec, b, offC0, offA, offB, n, nfp2, half);
  const int tid = threadIdx.x;
  const int by = blockIdx.y;
  const int c0 = by * 64;
  const int bx = blockIdx.x & 63;
  const int mode = blockIdx.x >> 6;

  if (mode == 1 && nfp2 == 1) {  // degenerate: answer is h[:, 0]
    if (bx == 0 && tid < 64)
      dout[(size_t)b * CH + c0 + tid] = h[(size_t)b * CH * LMAX + (size_t)(c0 + tid) * LMAX];
    return;
  }

  const int d0 = bx * 32;
  int dlo, dhi, soff;
  size_t base;
  if (mode == 0) { dlo = 0; dhi = half; soff = 0; base = offC0; }
  else { dlo = half >> 1; dhi = nfp2 >> 1; soff = half; base = offA; }
  if (d0 >= dhi || d0 + 32 <= dlo) return;

  const float* hb = h + (size_t)b * CH * LMAX;

#pragma unroll
  for (int q = 0; q < 8; ++q) {
    int id = q * 256 + tid;
    int cl = id >> 5;
    int dl = id & 31;
    int d = d0 + dl;
    bool ok = (d < dhi) && (d >= dlo);
    float2 v;
    v.x = 0.f; v.y = 0.f;
    if (ok) v = *(const float2*)(hb + (size_t)(c0 + cl) * LMAX + 2 * d + soff);
    unsigned u = (unsigned)h2u((_Float16)v.x) | ((unsigned)h2u((_Float16)v.y) << 16);
    int g = cl >> 2;
    *(unsigned*)(T + dl * 256 + ((g ^ (dl & 15)) << 4) + (cl & 3) * 4) = u;
  }
  __syncthreads();
#pragma unroll
  for (int qq = 0; qq < 2; ++qq) {
    int gid = qq * 256 + tid;
    int dl = gid >> 4;
    int s = gid & 15;
    int d = d0 + dl;
    if (d >= dhi || d < dlo) continue;
    uint4 val = *(const uint4*)(T + dl * 256 + ((s ^ (dl & 15)) << 4));
    size_t dst = base + ((size_t)d << 11) + (size_t)((2 * by + (s >> 3)) << 7) +
                 (((s & 7) ^ (d & 7)) << 4);
    *(uint4*)(ws + dst) = val;
  }
}

// ---------- big levels (0..4): single-pass fp16 MFMA GEMM + fused gate (r14, best) ----------
// 192x128 tile, 256 threads, 4 waves = 2 ch-groups x 2 col-groups. BK=64 (16 steps).
__global__ __launch_bounds__(256, 2) void mfma_level_k(const float* __restrict__ bias,
                                                       const int* __restrict__ Nvec,
                                                       char* __restrict__ ws,
                                                       float* __restrict__ dout,
                                                       int level, int tiles) {
  __shared__ char smem[81920];  // A: 2 x 24576 @0, B: 2 x 16384 @49152
  const int id = blockIdx.x;
  const int o0 = (id & 7) * 64;   // o-group pinned to XCD via id%8 (W slice L2-resident)
  const int r2 = id >> 3;
  const int xb = r2 % tiles;
  const int b = r2 / tiles;
  if (b >= BATCH) return;

  size_t offC0, offA, offB; int n, nfp2, half;
  layout(Nvec, b, offC0, offA, offB, n, nfp2, half);

  int cols;
  size_t inOff, outOff;
  if (level == 0) {
    if (half == 0) return;
    cols = half;
    inOff = offC0;
    outOff = offA;
  } else {
    int w = nfp2 >> (level - 1);
    if (w < 2) return;
    cols = w >> 1;
    inOff = (level & 1) ? offA : offB;
    outOff = (level & 1) ? offB : offA;
  }
  const bool fin = (level > 0) && ((nfp2 >> level) == 1);
  const int l0 = xb * 128;
  if (l0 >= cols) return;

  const int tid = threadIdx.x;
  const int lane = tid & 63, wid = tid >> 6;
  const int lane15 = lane & 15, lq = lane >> 4;
  const int rg = wid & 1, cg = wid >> 1;   // cg in {0,1}
  const char* inp = ws + inOff;

  unsigned aoff[6]; int adst[6];
#pragma unroll
  for (int q = 0; q < 6; ++q) {
    int d = q * 4096 + tid * 16;
    int r = d >> 7;                               // tile row 0..191
    int p = d & 127;                              // byte within 128-B row
    int o = ((r >> 6) << 9) + o0 + (r & 63);      // global output row
    aoff[q] = ((unsigned)o << 7) + p;
    adst[q] = q * 4096 + wid * 1024;
  }
  unsigned boff[4]; int bdst[4];
#pragma unroll
  for (int q = 0; q < 4; ++q) {
    int d = q * 4096 + tid * 16;
    int l = d >> 7;                               // col within tile 0..127
    int p = d & 127;
    int lc = l0 + l; if (lc > cols - 1) lc = cols - 1;
    boff[q] = ((unsigned)lc << 11) + p;
    bdst[q] = q * 4096 + wid * 1024;
  }

#define STAGE(st, sel) do {                                                  \
    char* Ab = smem + (sel) * 24576;                                         \
    char* Bb = smem + 49152 + (sel) * 16384;                                 \
    unsigned ka = (unsigned)(st) * 196608u;                                  \
    unsigned kb = (unsigned)(st) << 7;                                       \
    _Pragma("unroll") for (int q = 0; q < 6; ++q)                            \
      gload16(ws + ka + aoff[q], Ab + adst[q]);                              \
    _Pragma("unroll") for (int q = 0; q < 4; ++q)                            \
      gload16(inp + kb + boff[q], Bb + bdst[q]);                             \
  } while (0)

  f4v acc[6][4];
#pragma unroll
  for (int m = 0; m < 6; ++m)
#pragma unroll
    for (int cf = 0; cf < 4; ++cf) acc[m][cf] = (f4v){0.f, 0.f, 0.f, 0.f};

  STAGE(0, 0);
  __syncthreads();

#pragma unroll 1
  for (int st = 0; st < 16; ++st) {
    const int cur = st & 1;
    if (st + 1 < 16) STAGE(st + 1, cur ^ 1);  // prefetch overlaps this step's compute
    const char* Asb = smem + cur * 24576;
    const char* Bsb = smem + 49152 + cur * 16384;

#pragma unroll
    for (int s2 = 0; s2 < 2; ++s2) {
      const int oct = (s2 << 2) | lq;           // k-octant within the 64-k step
      h8v bh[4];
#pragma unroll
      for (int cf = 0; cf < 4; ++cf) {
        int ll = cg * 64 + cf * 16 + lane15;
        bh[cf] = *(const h8v*)(Bsb + ll * 128 + ((oct ^ (ll & 7)) << 4));
      }
#pragma unroll
      for (int m = 0; m < 6; ++m) {
        int rr = (m >> 1) * 64 + rg * 32 + (m & 1) * 16 + lane15;
        h8v ah = *(const h8v*)(Asb + rr * 128 + ((oct ^ (rr & 7)) << 4));
#pragma unroll
        for (int cf = 0; cf < 4; ++cf)
          acc[m][cf] = __builtin_amdgcn_mfma_f32_16x16x32_f16(ah, bh[cf], acc[m][cf], 0, 0, 0);
      }
    }
    __syncthreads();
  }
#undef STAGE

  // epilogue
  char* outp = ws + outOff;
#pragma unroll
  for (int s = 0; s < 2; ++s) {
#pragma unroll
    for (int cf = 0; cf < 4; ++cf) {
      f4v vl = acc[s][cf], vr = acc[2 + s][cf], vg = acc[4 + s][cf];
      int l = l0 + cg * 64 + cf * 16 + lane15;
      if (l >= cols) continue;
      int P = l >> 1, par = l & 1;
#pragma unroll
      for (int j = 0; j < 4; ++j) {
        int c = o0 + rg * 32 + s * 16 + lq * 4 + j;
        float zl = vl[j] + bias[c];
        float zr = vr[j] + bias[CH + c];
        float zg = vg[j] + bias[2 * CH + c];
        float g = 1.f / (1.f + __expf(-zg));
        float rt = 1.f - 2.f / (1.f + __expf(2.f * zr));
        float val = zl * g + rt * (1.f - g);
        if (fin) {
          if (l == 0) dout[(size_t)b * CH + c] = val;
        } else {
          int k = 2 * c + par;
          size_t byte = ((size_t)P << 11) + (size_t)((k >> 6) << 7) +
                        ((((k >> 3) & 7) ^ (P & 7)) << 4) + ((k & 7) << 1);
          *(unsigned short*)(outp + byte) = h2u((_Float16)val);
        }
      }
    }
  }
}

// ---------- small levels (5..12, cols <= 128): BK=128, 192x64 tile (r14, proven) ----------
__global__ __launch_bounds__(256, 2) void small_level_k(const float* __restrict__ bias,
                                                        const int* __restrict__ Nvec,
                                                        char* __restrict__ ws,
                                                        float* __restrict__ dout,
                                                        int level, int tiles) {
  __shared__ char smem[131072];  // A: 2 x 49152 @0, B: 2 x 16384 @98304
  const int id = blockIdx.x;
  const int o0 = (id & 7) * 64;
  const int r2 = id >> 3;
  const int xb = r2 % tiles;
  const int b = r2 / tiles;
  if (b >= BATCH) return;

  size_t offC0, offA, offB; int n, nfp2, half;
  layout(Nvec, b, offC0, offA, offB, n, nfp2, half);

  int w = nfp2 >> (level - 1);
  if (w < 2) return;
  const int cols = w >> 1;
  const size_t inOff = (level & 1) ? offA : offB;
  const size_t outOff = (level & 1) ? offB : offA;
  const bool fin = (cols == 1);
  const int l0 = xb * 64;
  if (l0 >= cols) return;

  const int tid = threadIdx.x;
  const int lane = tid & 63, wid = tid >> 6;
  const int lane15 = lane & 15, lq = lane >> 4;
  const int rg = wid & 1, cg = wid >> 1;
  const char* inp = ws + inOff;

  unsigned aoff[12]; int adst[12];
#pragma unroll
  for (int q = 0; q < 12; ++q) {
    int d = q * 4096 + tid * 16;
    int r = d >> 8;                               // tile row 0..191 (256 B rows)
    int p = d & 255;
    int o = ((r >> 6) << 9) + o0 + (r & 63);
    aoff[q] = (unsigned)(p >> 7) * 196608u + ((unsigned)o << 7) + (p & 127);
    adst[q] = q * 4096 + wid * 1024;
  }
  unsigned boff[4]; int bdst[4];
#pragma unroll
  for (int q = 0; q < 4; ++q) {
    int d = q * 4096 + tid * 16;
    int l = d >> 8;                               // col 0..63
    int p = d & 255;
    int lc = l0 + l; if (lc > cols - 1) lc = cols - 1;
    boff[q] = ((unsigned)lc << 11) + (unsigned)((p >> 7) << 7) + (p & 127);
    bdst[q] = q * 4096 + wid * 1024;
  }

#define STAGES(st, sel) do {                                                 \
    char* Ab = smem + (sel) * 49152;                                         \
    char* Bb = smem + 98304 + (sel) * 16384;                                 \
    unsigned ka = (unsigned)(st) * 393216u;                                  \
    unsigned kb = (unsigned)(st) << 8;                                       \
    _Pragma("unroll") for (int q = 0; q < 12; ++q)                           \
      gload16(ws + ka + aoff[q], Ab + adst[q]);                              \
    _Pragma("unroll") for (int q = 0; q < 4; ++q)                            \
      gload16(inp + kb + boff[q], Bb + bdst[q]);                             \
  } while (0)

  f4v acc[6][2];
#pragma unroll
  for (int m = 0; m < 6; ++m)
#pragma unroll
    for (int cf = 0; cf < 2; ++cf) acc[m][cf] = (f4v){0.f, 0.f, 0.f, 0.f};

  STAGES(0, 0);
  __syncthreads();

#pragma unroll 1
  for (int st = 0; st < 8; ++st) {
    const int cur = st & 1;
    if (st + 1 < 8) STAGES(st + 1, cur ^ 1);
    const char* Asb = smem + cur * 49152;
    const char* Bsb = smem + 98304 + cur * 16384;

#pragma unroll
    for (int sub = 0; sub < 2; ++sub) {
#pragma unroll
      for (int s2 = 0; s2 < 2; ++s2) {
        const int oct = (s2 << 2) | lq;
        h8v bh[2];
#pragma unroll
        for (int cf = 0; cf < 2; ++cf) {
          int ll = cg * 32 + cf * 16 + lane15;
          bh[cf] = *(const h8v*)(Bsb + ll * 256 + sub * 128 + ((oct ^ (ll & 7)) << 4));
        }
#pragma unroll
        for (int m = 0; m < 6; ++m) {
          int rr = (m >> 1) * 64 + rg * 32 + (m & 1) * 16 + lane15;
          h8v ah = *(const h8v*)(Asb + rr * 256 + sub * 128 + ((oct ^ (rr & 7)) << 4));
#pragma unroll
          for (int cf = 0; cf < 2; ++cf)
            acc[m][cf] = __builtin_amdgcn_mfma_f32_16x16x32_f16(ah, bh[cf], acc[m][cf], 0, 0, 0);
        }
      }
    }
    __syncthreads();
  }
#undef STAGES

  char* outp = ws + outOff;
#pragma unroll
  for (int s = 0; s < 2; ++s) {
#pragma unroll
    for (int cf = 0; cf < 2; ++cf) {
      f4v vl = acc[s][cf], vr = acc[2 + s][cf], vg = acc[4 + s][cf];
      int l = l0 + cg * 32 + cf * 16 + lane15;
      if (l >= cols) continue;
      int P = l >> 1, par = l & 1;
#pragma unroll
      for (int j = 0; j < 4; ++j) {
        int c = o0 + rg * 32 + s * 16 + lq * 4 + j;
        float zl = vl[j] + bias[c];
        float zr = vr[j] + bias[CH + c];
        float zg = vg[j] + bias[2 * CH + c];
        float g = 1.f / (1.f + __expf(-zg));
        float rt = 1.f - 2.f / (1.f + __expf(2.f * zr));
        float val = zl * g + rt * (1.f - g);
        if (fin) {
          if (l == 0) dout[(size_t)b * CH + c] = val;
        } else {
          int k = 2 * c + par;
          size_t byte = ((size_t)P << 11) + (size_t)((k >> 6) << 7) +
                        ((((k >> 3) & 7) ^ (P & 7)) << 4) + ((k & 7) << 1);
          *(unsigned short*)(outp + byte) = h2u((_Float16)val);
        }
      }
    }
  }
}

extern "C" void kernel_launch(void* const* d_in, const int* in_sizes, int n_in,
                              void* d_out, int out_size, void* d_ws, size_t ws_size,
                              hipStream_t stream) {
  const float* h = (const float*)d_in[0];
  const float* W = (const float*)d_in[1];
  const float* bias = (const float*)d_in[2];
  const int* Nvec = (const int*)d_in[3];
  float* dout = (float*)d_out;
  char* ws = (char*)d_ws;

  prep_w_k<<<dim3(96), 256, 0, stream>>>(W, ws);
  reorg_h_k<<<dim3(128, 8, BATCH), 256, 0, stream>>>(h, Nvec, ws, dout);

  // level 0: max half = 952 -> 8 tiles of 128
  mfma_level_k<<<dim3(8 * 8 * BATCH), 256, 0, stream>>>(bias, Nvec, ws, dout, 0, 8);
  // big tree levels 1..4 (cols up to 2048)
  for (int lev = 1; lev <= 4; ++lev) {
    int tiles = (LMAX >> lev) / 128;
    mfma_level_k<<<dim3(tiles * 8 * BATCH), 256, 0, stream>>>(bias, Nvec, ws, dout, lev, tiles);
  }
  // small tree levels 5..12 (cols <= 128): BK=128 kernel, 64-col tiles
  for (int lev = 5; lev <= 12; ++lev) {
    int colsmax = LMAX >> lev;
    int tiles = (colsmax + 63) / 64; if (tiles < 1) tiles = 1;
    small_level_k<<<dim3(tiles * 8 * BATCH), 256, 0, stream>>>(bias, Nvec, ws, dout, lev, tiles);
  }
}

// Round 22
// 456.887 us; speedup vs baseline: 1.1704x; 1.0008x over previous
//
#include <hip/hip_runtime.h>

#define BATCH 16
#define CH 512
#define OC 1536
#define KDIM 1024
#define LMAX 4096
#define WGLOB_SZ 3145728  // 16 steps * 1536 rows * 128 B (fp16, 64 k per step)

typedef __attribute__((ext_vector_type(8))) _Float16 h8v;
typedef __attribute__((ext_vector_type(4))) float f4v;

__device__ __forceinline__ int nfp2_of(int n) { return 1 << (31 - __clz(n)); }

__device__ __forceinline__ unsigned short h2u(_Float16 h) {
  union { _Float16 h; unsigned short u; } v; v.h = h; return v.u;
}

// per-batch arena layout; records are 2KB (1024 fp16)
// record: chunk = k>>6 (128 B), slot s in chunk holds k-octant (s ^ (d&7)), 8 fp16
__device__ __forceinline__ void layout(const int* __restrict__ Nvec, int b,
                                       size_t& offC0, size_t& offA, size_t& offB,
                                       int& n, int& nfp2, int& half) {
  size_t c0t = 0, at = 0, bt = 0, c0o = 0, ao = 0, bo = 0;
  n = 2; nfp2 = 2; half = 0;
#pragma unroll 1
  for (int i = 0; i < BATCH; ++i) {
    int ni = Nvec[i];
    int f = nfp2_of(ni);
    int hf = ni - f;
    size_t cs = (size_t)((hf + 127) & ~127) << 11;
    size_t as = (size_t)(f >> 1) << 11;
    size_t bs = (size_t)(f >> 2) << 11;
    if (i < b) { c0o += cs; ao += as; bo += bs; }
    if (i == b) { n = ni; nfp2 = f; half = hf; }
    c0t += cs; at += as; bt += bs;
  }
  offC0 = (size_t)WGLOB_SZ + c0o;
  offA = (size_t)WGLOB_SZ + c0t + ao;
  offB = (size_t)WGLOB_SZ + c0t + at + bo;
}

__device__ __forceinline__ void gload16(const void* g, void* l) {
  __builtin_amdgcn_global_load_lds((const __attribute__((address_space(1))) void*)g,
                                   (__attribute__((address_space(3))) void*)l, 16, 0, 0);
}

// ---------- W prep: W[o][k] fp32 -> Wglob[step][o][128 B], slot s = octant s^(o&7) ----------
__global__ __launch_bounds__(256) void prep_w_k(const float* __restrict__ W, char* __restrict__ ws) {
  int idx = blockIdx.x * 256 + threadIdx.x;  // idx = step*1536 + o
  if (idx >= 16 * 1536) return;
  int step = idx / 1536;
  int o = idx - step * 1536;
  const float* src = W + (size_t)o * KDIM + step * 64;
  unsigned short hb[64];
#pragma unroll
  for (int t = 0; t < 64; ++t) hb[t] = h2u((_Float16)src[t]);
  uint4* d4 = (uint4*)(ws + ((size_t)idx << 7));
#pragma unroll
  for (int s = 0; s < 8; ++s) {
    int oc = (s ^ (o & 7)) * 8;
    uint4 v;
    v.x = (unsigned)hb[oc + 0] | ((unsigned)hb[oc + 1] << 16);
    v.y = (unsigned)hb[oc + 2] | ((unsigned)hb[oc + 3] << 16);
    v.z = (unsigned)hb[oc + 4] | ((unsigned)hb[oc + 5] << 16);
    v.w = (unsigned)hb[oc + 6] | ((unsigned)hb[oc + 7] << 16);
    d4[s] = v;
  }
}

// ---------- h reorg: coalesced read + LDS transpose -> fp16 records ----------
// blockIdx.x in [0,128): mode = x>>6 (0: conv pairs -> C0, 1: suffix -> bufA)
__global__ __launch_bounds__(256) void reorg_h_k(const float* __restrict__ h,
                                                 const int* __restrict__ Nvec,
                                                 char* __restrict__ ws,
                                                 float* __restrict__ dout) {
  __shared__ char T[32 * 256];  // 8 KB
  const int b = blockIdx.z;
  size_t offC0, offA, offB; int n, nfp2, half;
  layout(Nvec, b, offC0, offA, offB, n, nfp2, half);
  const int tid = threadIdx.x;
  const int by = blockIdx.y;
  const int c0 = by * 64;
  const int bx = blockIdx.x & 63;
  const int mode = blockIdx.x >> 6;

  if (mode == 1 && nfp2 == 1) {  // degenerate: answer is h[:, 0]
    if (bx == 0 && tid < 64)
      dout[(size_t)b * CH + c0 + tid] = h[(size_t)b * CH * LMAX + (size_t)(c0 + tid) * LMAX];
    return;
  }

  const int d0 = bx * 32;
  int dlo, dhi, soff;
  size_t base;
  if (mode == 0) { dlo = 0; dhi = half; soff = 0; base = offC0; }
  else { dlo = half >> 1; dhi = nfp2 >> 1; soff = half; base = offA; }
  if (d0 >= dhi || d0 + 32 <= dlo) return;

  const float* hb = h + (size_t)b * CH * LMAX;

#pragma unroll
  for (int q = 0; q < 8; ++q) {
    int id = q * 256 + tid;
    int cl = id >> 5;
    int dl = id & 31;
    int d = d0 + dl;
    bool ok = (d < dhi) && (d >= dlo);
    float2 v;
    v.x = 0.f; v.y = 0.f;
    if (ok) v = *(const float2*)(hb + (size_t)(c0 + cl) * LMAX + 2 * d + soff);
    unsigned u = (unsigned)h2u((_Float16)v.x) | ((unsigned)h2u((_Float16)v.y) << 16);
    int g = cl >> 2;
    *(unsigned*)(T + dl * 256 + ((g ^ (dl & 15)) << 4) + (cl & 3) * 4) = u;
  }
  __syncthreads();
#pragma unroll
  for (int qq = 0; qq < 2; ++qq) {
    int gid = qq * 256 + tid;
    int dl = gid >> 4;
    int s = gid & 15;
    int d = d0 + dl;
    if (d >= dhi || d < dlo) continue;
    uint4 val = *(const uint4*)(T + dl * 256 + ((s ^ (dl & 15)) << 4));
    size_t dst = base + ((size_t)d << 11) + (size_t)((2 * by + (s >> 3)) << 7) +
                 (((s & 7) ^ (d & 7)) << 4);
    *(uint4*)(ws + dst) = val;
  }
}

// ---------- big levels (0..4): single-pass fp16 MFMA GEMM + fused gate (r14, best) ----------
// 192x128 tile, 256 threads, 4 waves = 2 ch-groups x 2 col-groups. BK=64 (16 steps).
__global__ __launch_bounds__(256, 2) void mfma_level_k(const float* __restrict__ bias,
                                                       const int* __restrict__ Nvec,
                                                       char* __restrict__ ws,
                                                       float* __restrict__ dout,
                                                       int level, int tiles) {
  __shared__ char smem[81920];  // A: 2 x 24576 @0, B: 2 x 16384 @49152
  const int id = blockIdx.x;
  const int o0 = (id & 7) * 64;   // o-group pinned to XCD via id%8 (W slice L2-resident)
  const int r2 = id >> 3;
  const int xb = r2 % tiles;
  const int b = r2 / tiles;
  if (b >= BATCH) return;

  size_t offC0, offA, offB; int n, nfp2, half;
  layout(Nvec, b, offC0, offA, offB, n, nfp2, half);

  int cols;
  size_t inOff, outOff;
  if (level == 0) {
    if (half == 0) return;
    cols = half;
    inOff = offC0;
    outOff = offA;
  } else {
    int w = nfp2 >> (level - 1);
    if (w < 2) return;
    cols = w >> 1;
    inOff = (level & 1) ? offA : offB;
    outOff = (level & 1) ? offB : offA;
  }
  const bool fin = (level > 0) && ((nfp2 >> level) == 1);
  const int l0 = xb * 128;
  if (l0 >= cols) return;

  const int tid = threadIdx.x;
  const int lane = tid & 63, wid = tid >> 6;
  const int lane15 = lane & 15, lq = lane >> 4;
  const int rg = wid & 1, cg = wid >> 1;   // cg in {0,1}
  const char* inp = ws + inOff;

  unsigned aoff[6]; int adst[6];
#pragma unroll
  for (int q = 0; q < 6; ++q) {
    int d = q * 4096 + tid * 16;
    int r = d >> 7;                               // tile row 0..191
    int p = d & 127;                              // byte within 128-B row
    int o = ((r >> 6) << 9) + o0 + (r & 63);      // global output row
    aoff[q] = ((unsigned)o << 7) + p;
    adst[q] = q * 4096 + wid * 1024;
  }
  unsigned boff[4]; int bdst[4];
#pragma unroll
  for (int q = 0; q < 4; ++q) {
    int d = q * 4096 + tid * 16;
    int l = d >> 7;                               // col within tile 0..127
    int p = d & 127;
    int lc = l0 + l; if (lc > cols - 1) lc = cols - 1;
    boff[q] = ((unsigned)lc << 11) + p;
    bdst[q] = q * 4096 + wid * 1024;
  }

#define STAGE(st, sel) do {                                                  \
    char* Ab = smem + (sel) * 24576;                                         \
    char* Bb = smem + 49152 + (sel) * 16384;                                 \
    unsigned ka = (unsigned)(st) * 196608u;                                  \
    unsigned kb = (unsigned)(st) << 7;                                       \
    _Pragma("unroll") for (int q = 0; q < 6; ++q)                            \
      gload16(ws + ka + aoff[q], Ab + adst[q]);                              \
    _Pragma("unroll") for (int q = 0; q < 4; ++q)                            \
      gload16(inp + kb + boff[q], Bb + bdst[q]);                             \
  } while (0)

  f4v acc[6][4];
#pragma unroll
  for (int m = 0; m < 6; ++m)
#pragma unroll
    for (int cf = 0; cf < 4; ++cf) acc[m][cf] = (f4v){0.f, 0.f, 0.f, 0.f};

  STAGE(0, 0);
  __syncthreads();

#pragma unroll 1
  for (int st = 0; st < 16; ++st) {
    const int cur = st & 1;
    if (st + 1 < 16) STAGE(st + 1, cur ^ 1);  // prefetch overlaps this step's compute
    const char* Asb = smem + cur * 24576;
    const char* Bsb = smem + 49152 + cur * 16384;

#pragma unroll
    for (int s2 = 0; s2 < 2; ++s2) {
      const int oct = (s2 << 2) | lq;           // k-octant within the 64-k step
      h8v bh[4];
#pragma unroll
      for (int cf = 0; cf < 4; ++cf) {
        int ll = cg * 64 + cf * 16 + lane15;
        bh[cf] = *(const h8v*)(Bsb + ll * 128 + ((oct ^ (ll & 7)) << 4));
      }
#pragma unroll
      for (int m = 0; m < 6; ++m) {
        int rr = (m >> 1) * 64 + rg * 32 + (m & 1) * 16 + lane15;
        h8v ah = *(const h8v*)(Asb + rr * 128 + ((oct ^ (rr & 7)) << 4));
#pragma unroll
        for (int cf = 0; cf < 4; ++cf)
          acc[m][cf] = __builtin_amdgcn_mfma_f32_16x16x32_f16(ah, bh[cf], acc[m][cf], 0, 0, 0);
      }
    }
    __syncthreads();
  }
#undef STAGE

  // epilogue
  char* outp = ws + outOff;
#pragma unroll
  for (int s = 0; s < 2; ++s) {
#pragma unroll
    for (int cf = 0; cf < 4; ++cf) {
      f4v vl = acc[s][cf], vr = acc[2 + s][cf], vg = acc[4 + s][cf];
      int l = l0 + cg * 64 + cf * 16 + lane15;
      if (l >= cols) continue;
      int P = l >> 1, par = l & 1;
#pragma unroll
      for (int j = 0; j < 4; ++j) {
        int c = o0 + rg * 32 + s * 16 + lq * 4 + j;
        float zl = vl[j] + bias[c];
        float zr = vr[j] + bias[CH + c];
        float zg = vg[j] + bias[2 * CH + c];
        float g = 1.f / (1.f + __expf(-zg));
        float rt = 1.f - 2.f / (1.f + __expf(2.f * zr));
        float val = zl * g + rt * (1.f - g);
        if (fin) {
          if (l == 0) dout[(size_t)b * CH + c] = val;
        } else {
          int k = 2 * c + par;
          size_t byte = ((size_t)P << 11) + (size_t)((k >> 6) << 7) +
                        ((((k >> 3) & 7) ^ (P & 7)) << 4) + ((k & 7) << 1);
          *(unsigned short*)(outp + byte) = h2u((_Float16)val);
        }
      }
    }
  }
}

// ---------- small levels (5..12, cols <= 128): BK=128, 192x64 tile (r14, proven) ----------
__global__ __launch_bounds__(256, 2) void small_level_k(const float* __restrict__ bias,
                                                        const int* __restrict__ Nvec,
                                                        char* __restrict__ ws,
                                                        float* __restrict__ dout,
                                                        int level, int tiles) {
  __shared__ char smem[131072];  // A: 2 x 49152 @0, B: 2 x 16384 @98304
  const int id = blockIdx.x;
  const int o0 = (id & 7) * 64;
  const int r2 = id >> 3;
  const int xb = r2 % tiles;
  const int b = r2 / tiles;
  if (b >= BATCH) return;

  size_t offC0, offA, offB; int n, nfp2, half;
  layout(Nvec, b, offC0, offA, offB, n, nfp2, half);

  int w = nfp2 >> (level - 1);
  if (w < 2) return;
  const int cols = w >> 1;
  const size_t inOff = (level & 1) ? offA : offB;
  const size_t outOff = (level & 1) ? offB : offA;
  const bool fin = (cols == 1);
  const int l0 = xb * 64;
  if (l0 >= cols) return;

  const int tid = threadIdx.x;
  const int lane = tid & 63, wid = tid >> 6;
  const int lane15 = lane & 15, lq = lane >> 4;
  const int rg = wid & 1, cg = wid >> 1;
  const char* inp = ws + inOff;

  unsigned aoff[12]; int adst[12];
#pragma unroll
  for (int q = 0; q < 12; ++q) {
    int d = q * 4096 + tid * 16;
    int r = d >> 8;                               // tile row 0..191 (256 B rows)
    int p = d & 255;
    int o = ((r >> 6) << 9) + o0 + (r & 63);
    aoff[q] = (unsigned)(p >> 7) * 196608u + ((unsigned)o << 7) + (p & 127);
    adst[q] = q * 4096 + wid * 1024;
  }
  unsigned boff[4]; int bdst[4];
#pragma unroll
  for (int q = 0; q < 4; ++q) {
    int d = q * 4096 + tid * 16;
    int l = d >> 8;                               // col 0..63
    int p = d & 255;
    int lc = l0 + l; if (lc > cols - 1) lc = cols - 1;
    boff[q] = ((unsigned)lc << 11) + (unsigned)((p >> 7) << 7) + (p & 127);
    bdst[q] = q * 4096 + wid * 1024;
  }

#define STAGES(st, sel) do {                                                 \
    char* Ab = smem + (sel) * 49152;                                         \
    char* Bb = smem + 98304 + (sel) * 16384;                                 \
    unsigned ka = (unsigned)(st) * 393216u;                                  \
    unsigned kb = (unsigned)(st) << 8;                                       \
    _Pragma("unroll") for (int q = 0; q < 12; ++q)                           \
      gload16(ws + ka + aoff[q], Ab + adst[q]);                              \
    _Pragma("unroll") for (int q = 0; q < 4; ++q)                            \
      gload16(inp + kb + boff[q], Bb + bdst[q]);                             \
  } while (0)

  f4v acc[6][2];
#pragma unroll
  for (int m = 0; m < 6; ++m)
#pragma unroll
    for (int cf = 0; cf < 2; ++cf) acc[m][cf] = (f4v){0.f, 0.f, 0.f, 0.f};

  STAGES(0, 0);
  __syncthreads();

#pragma unroll 1
  for (int st = 0; st < 8; ++st) {
    const int cur = st & 1;
    if (st + 1 < 8) STAGES(st + 1, cur ^ 1);
    const char* Asb = smem + cur * 49152;
    const char* Bsb = smem + 98304 + cur * 16384;

#pragma unroll
    for (int sub = 0; sub < 2; ++sub) {
#pragma unroll
      for (int s2 = 0; s2 < 2; ++s2) {
        const int oct = (s2 << 2) | lq;
        h8v bh[2];
#pragma unroll
        for (int cf = 0; cf < 2; ++cf) {
          int ll = cg * 32 + cf * 16 + lane15;
          bh[cf] = *(const h8v*)(Bsb + ll * 256 + sub * 128 + ((oct ^ (ll & 7)) << 4));
        }
#pragma unroll
        for (int m = 0; m < 6; ++m) {
          int rr = (m >> 1) * 64 + rg * 32 + (m & 1) * 16 + lane15;
          h8v ah = *(const h8v*)(Asb + rr * 256 + sub * 128 + ((oct ^ (rr & 7)) << 4));
#pragma unroll
          for (int cf = 0; cf < 2; ++cf)
            acc[m][cf] = __builtin_amdgcn_mfma_f32_16x16x32_f16(ah, bh[cf], acc[m][cf], 0, 0, 0);
        }
      }
    }
    __syncthreads();
  }
#undef STAGES

  char* outp = ws + outOff;
#pragma unroll
  for (int s = 0; s < 2; ++s) {
#pragma unroll
    for (int cf = 0; cf < 2; ++cf) {
      f4v vl = acc[s][cf], vr = acc[2 + s][cf], vg = acc[4 + s][cf];
      int l = l0 + cg * 32 + cf * 16 + lane15;
      if (l >= cols) continue;
      int P = l >> 1, par = l & 1;
#pragma unroll
      for (int j = 0; j < 4; ++j) {
        int c = o0 + rg * 32 + s * 16 + lq * 4 + j;
        float zl = vl[j] + bias[c];
        float zr = vr[j] + bias[CH + c];
        float zg = vg[j] + bias[2 * CH + c];
        float g = 1.f / (1.f + __expf(-zg));
        float rt = 1.f - 2.f / (1.f + __expf(2.f * zr));
        float val = zl * g + rt * (1.f - g);
        if (fin) {
          if (l == 0) dout[(size_t)b * CH + c] = val;
        } else {
          int k = 2 * c + par;
          size_t byte = ((size_t)P << 11) + (size_t)((k >> 6) << 7) +
                        ((((k >> 3) & 7) ^ (P & 7)) << 4) + ((k & 7) << 1);
          *(unsigned short*)(outp + byte) = h2u((_Float16)val);
        }
      }
    }
  }
}

extern "C" void kernel_launch(void* const* d_in, const int* in_sizes, int n_in,
                              void* d_out, int out_size, void* d_ws, size_t ws_size,
                              hipStream_t stream) {
  const float* h = (const float*)d_in[0];
  const float* W = (const float*)d_in[1];
  const float* bias = (const float*)d_in[2];
  const int* Nvec = (const int*)d_in[3];
  float* dout = (float*)d_out;
  char* ws = (char*)d_ws;

  prep_w_k<<<dim3(96), 256, 0, stream>>>(W, ws);
  reorg_h_k<<<dim3(128, 8, BATCH), 256, 0, stream>>>(h, Nvec, ws, dout);

  // level 0: max half = 952 -> 8 tiles of 128
  mfma_level_k<<<dim3(8 * 8 * BATCH), 256, 0, stream>>>(bias, Nvec, ws, dout, 0, 8);
  // big tree levels 1..4 (cols up to 2048)
  for (int lev = 1; lev <= 4; ++lev) {
    int tiles = (LMAX >> lev) / 128;
    mfma_level_k<<<dim3(tiles * 8 * BATCH), 256, 0, stream>>>(bias, Nvec, ws, dout, lev, tiles);
  }
  // small tree levels 5..12 (cols <= 128): BK=128 kernel, 64-col tiles
  for (int lev = 5; lev <= 12; ++lev) {
    int colsmax = LMAX >> lev;
    int tiles = (colsmax + 63) / 64; if (tiles < 1) tiles = 1;
    small_level_k<<<dim3(tiles * 8 * BATCH), 256, 0, stream>>>(bias, Nvec, ws, dout, lev, tiles);
  }
}

// Round 23
// 456.584 us; speedup vs baseline: 1.1712x; 1.0007x over previous
//
#include <hip/hip_runtime.h>

#define BATCH 16
#define CH 512
#define OC 1536
#define KDIM 1024
#define LMAX 4096
#define WGLOB_SZ 3145728  // 16 steps * 1536 rows * 128 B (fp16, 64 k per step)

typedef __attribute__((ext_vector_type(8))) _Float16 h8v;
typedef __attribute__((ext_vector_type(4))) float f4v;

__device__ __forceinline__ int nfp2_of(int n) { return 1 << (31 - __clz(n)); }

__device__ __forceinline__ unsigned short h2u(_Float16 h) {
  union { _Float16 h; unsigned short u; } v; v.h = h; return v.u;
}

// per-batch arena layout; records are 2KB (1024 fp16)
// record: chunk = k>>6 (128 B), slot s in chunk holds k-octant (s ^ (d&7)), 8 fp16
__device__ __forceinline__ void layout(const int* __restrict__ Nvec, int b,
                                       size_t& offC0, size_t& offA, size_t& offB,
                                       int& n, int& nfp2, int& half) {
  size_t c0t = 0, at = 0, bt = 0, c0o = 0, ao = 0, bo = 0;
  n = 2; nfp2 = 2; half = 0;
#pragma unroll 1
  for (int i = 0; i < BATCH; ++i) {
    int ni = Nvec[i];
    int f = nfp2_of(ni);
    int hf = ni - f;
    size_t cs = (size_t)((hf + 127) & ~127) << 11;
    size_t as = (size_t)(f >> 1) << 11;
    size_t bs = (size_t)(f >> 2) << 11;
    if (i < b) { c0o += cs; ao += as; bo += bs; }
    if (i == b) { n = ni; nfp2 = f; half = hf; }
    c0t += cs; at += as; bt += bs;
  }
  offC0 = (size_t)WGLOB_SZ + c0o;
  offA = (size_t)WGLOB_SZ + c0t + ao;
  offB = (size_t)WGLOB_SZ + c0t + at + bo;
}

__device__ __forceinline__ void gload16(const void* g, void* l) {
  __builtin_amdgcn_global_load_lds((const __attribute__((address_space(1))) void*)g,
                                   (__attribute__((address_space(3))) void*)l, 16, 0, 0);
}

// ---------- W prep: W[o][k] fp32 -> Wglob[step][o][128 B], slot s = octant s^(o&7) ----------
__global__ __launch_bounds__(256) void prep_w_k(const float* __restrict__ W, char* __restrict__ ws) {
  int idx = blockIdx.x * 256 + threadIdx.x;  // idx = step*1536 + o
  if (idx >= 16 * 1536) return;
  int step = idx / 1536;
  int o = idx - step * 1536;
  const float* src = W + (size_t)o * KDIM + step * 64;
  unsigned short hb[64];
#pragma unroll
  for (int t = 0; t < 64; ++t) hb[t] = h2u((_Float16)src[t]);
  uint4* d4 = (uint4*)(ws + ((size_t)idx << 7));
#pragma unroll
  for (int s = 0; s < 8; ++s) {
    int oc = (s ^ (o & 7)) * 8;
    uint4 v;
    v.x = (unsigned)hb[oc + 0] | ((unsigned)hb[oc + 1] << 16);
    v.y = (unsigned)hb[oc + 2] | ((unsigned)hb[oc + 3] << 16);
    v.z = (unsigned)hb[oc + 4] | ((unsigned)hb[oc + 5] << 16);
    v.w = (unsigned)hb[oc + 6] | ((unsigned)hb[oc + 7] << 16);
    d4[s] = v;
  }
}

// ---------- h reorg: coalesced read + LDS transpose -> fp16 records ----------
// blockIdx.x in [0,128): mode = x>>6 (0: conv pairs -> C0, 1: suffix -> bufA)
__global__ __launch_bounds__(256) void reorg_h_k(const float* __restrict__ h,
                                                 const int* __restrict__ Nvec,
                                                 char* __restrict__ ws,
                                                 float* __restrict__ dout) {
  __shared__ char T[32 * 256];  // 8 KB
  const int b = blockIdx.z;
  size_t offC0, offA, offB; int n, nfp2, half;
  layout(Nvec, b, offC0, offA, offB, n, nfp2, half);
  const int tid = threadIdx.x;
  const int by = blockIdx.y;
  const int c0 = by * 64;
  const int bx = blockIdx.x & 63;
  const int mode = blockIdx.x >> 6;

  if (mode == 1 && nfp2 == 1) {  // degenerate: answer is h[:, 0]
    if (bx == 0 && tid < 64)
      dout[(size_t)b * CH + c0 + tid] = h[(size_t)b * CH * LMAX + (size_t)(c0 + tid) * LMAX];
    return;
  }

  const int d0 = bx * 32;
  int dlo, dhi, soff;
  size_t base;
  if (mode == 0) { dlo = 0; dhi = half; soff = 0; base = offC0; }
  else { dlo = half >> 1; dhi = nfp2 >> 1; soff = half; base = offA; }
  if (d0 >= dhi || d0 + 32 <= dlo) return;

  const float* hb = h + (size_t)b * CH * LMAX;

#pragma unroll
  for (int q = 0; q < 8; ++q) {
    int id = q * 256 + tid;
    int cl = id >> 5;
    int dl = id & 31;
    int d = d0 + dl;
    bool ok = (d < dhi) && (d >= dlo);
    float2 v;
    v.x = 0.f; v.y = 0.f;
    if (ok) v = *(const float2*)(hb + (size_t)(c0 + cl) * LMAX + 2 * d + soff);
    unsigned u = (unsigned)h2u((_Float16)v.x) | ((unsigned)h2u((_Float16)v.y) << 16);
    int g = cl >> 2;
    *(unsigned*)(T + dl * 256 + ((g ^ (dl & 15)) << 4) + (cl & 3) * 4) = u;
  }
  __syncthreads();
#pragma unroll
  for (int qq = 0; qq < 2; ++qq) {
    int gid = qq * 256 + tid;
    int dl = gid >> 4;
    int s = gid & 15;
    int d = d0 + dl;
    if (d >= dhi || d < dlo) continue;
    uint4 val = *(const uint4*)(T + dl * 256 + ((s ^ (dl & 15)) << 4));
    size_t dst = base + ((size_t)d << 11) + (size_t)((2 * by + (s >> 3)) << 7) +
                 (((s & 7) ^ (d & 7)) << 4);
    *(uint4*)(ws + dst) = val;
  }
}

// ---------- big levels (0..4): single-pass fp16 MFMA GEMM + fused gate ----------
// 192x128 tile, 256 threads, 4 waves = 2 ch-groups x 2 col-groups. BK=64 (16 steps).
// Block-id decode pins a B col-tile (all 8 o-groups) to ONE XCD (t%8 = id&7):
// B fetched into that XCD's L2 once, hit 7x; W (3.1 MB, single fp16) fits L2 too.
__global__ __launch_bounds__(256, 2) void mfma_level_k(const float* __restrict__ bias,
                                                       const int* __restrict__ Nvec,
                                                       char* __restrict__ ws,
                                                       float* __restrict__ dout,
                                                       int level, int tiles) {
  __shared__ char smem[81920];  // A: 2 x 24576 @0, B: 2 x 16384 @49152
  const int id = blockIdx.x;
  const int o0 = ((id >> 3) & 7) * 64;            // o-group
  const int t = ((id >> 6) << 3) | (id & 7);      // global tile index = b*tiles + xb
  const int xb = t % tiles;
  const int b = t / tiles;
  if (b >= BATCH) return;

  size_t offC0, offA, offB; int n, nfp2, half;
  layout(Nvec, b, offC0, offA, offB, n, nfp2, half);

  int cols;
  size_t inOff, outOff;
  if (level == 0) {
    if (half == 0) return;
    cols = half;
    inOff = offC0;
    outOff = offA;
  } else {
    int w = nfp2 >> (level - 1);
    if (w < 2) return;
    cols = w >> 1;
    inOff = (level & 1) ? offA : offB;
    outOff = (level & 1) ? offB : offA;
  }
  const bool fin = (level > 0) && ((nfp2 >> level) == 1);
  const int l0 = xb * 128;
  if (l0 >= cols) return;

  const int tid = threadIdx.x;
  const int lane = tid & 63, wid = tid >> 6;
  const int lane15 = lane & 15, lq = lane >> 4;
  const int rg = wid & 1, cg = wid >> 1;   // cg in {0,1}
  const char* inp = ws + inOff;

  unsigned aoff[6]; int adst[6];
#pragma unroll
  for (int q = 0; q < 6; ++q) {
    int d = q * 4096 + tid * 16;
    int r = d >> 7;                               // tile row 0..191
    int p = d & 127;                              // byte within 128-B row
    int o = ((r >> 6) << 9) + o0 + (r & 63);      // global output row
    aoff[q] = ((unsigned)o << 7) + p;
    adst[q] = q * 4096 + wid * 1024;
  }
  unsigned boff[4]; int bdst[4];
#pragma unroll
  for (int q = 0; q < 4; ++q) {
    int d = q * 4096 + tid * 16;
    int l = d >> 7;                               // col within tile 0..127
    int p = d & 127;
    int lc = l0 + l; if (lc > cols - 1) lc = cols - 1;
    boff[q] = ((unsigned)lc << 11) + p;
    bdst[q] = q * 4096 + wid * 1024;
  }

#define STAGE(st, sel) do {                                                  \
    char* Ab = smem + (sel) * 24576;                                         \
    char* Bb = smem + 49152 + (sel) * 16384;                                 \
    unsigned ka = (unsigned)(st) * 196608u;                                  \
    unsigned kb = (unsigned)(st) << 7;                                       \
    _Pragma("unroll") for (int q = 0; q < 6; ++q)                            \
      gload16(ws + ka + aoff[q], Ab + adst[q]);                              \
    _Pragma("unroll") for (int q = 0; q < 4; ++q)                            \
      gload16(inp + kb + boff[q], Bb + bdst[q]);                             \
  } while (0)

  f4v acc[6][4];
#pragma unroll
  for (int m = 0; m < 6; ++m)
#pragma unroll
    for (int cf = 0; cf < 4; ++cf) acc[m][cf] = (f4v){0.f, 0.f, 0.f, 0.f};

  STAGE(0, 0);
  __syncthreads();

#pragma unroll 1
  for (int st = 0; st < 16; ++st) {
    const int cur = st & 1;
    if (st + 1 < 16) STAGE(st + 1, cur ^ 1);  // prefetch overlaps this step's compute
    const char* Asb = smem + cur * 24576;
    const char* Bsb = smem + 49152 + cur * 16384;

#pragma unroll
    for (int s2 = 0; s2 < 2; ++s2) {
      const int oct = (s2 << 2) | lq;           // k-octant within the 64-k step
      h8v bh[4];
#pragma unroll
      for (int cf = 0; cf < 4; ++cf) {
        int ll = cg * 64 + cf * 16 + lane15;
        bh[cf] = *(const h8v*)(Bsb + ll * 128 + ((oct ^ (ll & 7)) << 4));
      }
#pragma unroll
      for (int m = 0; m < 6; ++m) {
        int rr = (m >> 1) * 64 + rg * 32 + (m & 1) * 16 + lane15;
        h8v ah = *(const h8v*)(Asb + rr * 128 + ((oct ^ (rr & 7)) << 4));
#pragma unroll
        for (int cf = 0; cf < 4; ++cf)
          acc[m][cf] = __builtin_amdgcn_mfma_f32_16x16x32_f16(ah, bh[cf], acc[m][cf], 0, 0, 0);
      }
    }
    __syncthreads();
  }
#undef STAGE

  // epilogue
  char* outp = ws + outOff;
#pragma unroll
  for (int s = 0; s < 2; ++s) {
#pragma unroll
    for (int cf = 0; cf < 4; ++cf) {
      f4v vl = acc[s][cf], vr = acc[2 + s][cf], vg = acc[4 + s][cf];
      int l = l0 + cg * 64 + cf * 16 + lane15;
      if (l >= cols) continue;
      int P = l >> 1, par = l & 1;
#pragma unroll
      for (int j = 0; j < 4; ++j) {
        int c = o0 + rg * 32 + s * 16 + lq * 4 + j;
        float zl = vl[j] + bias[c];
        float zr = vr[j] + bias[CH + c];
        float zg = vg[j] + bias[2 * CH + c];
        float g = 1.f / (1.f + __expf(-zg));
        float rt = 1.f - 2.f / (1.f + __expf(2.f * zr));
        float val = zl * g + rt * (1.f - g);
        if (fin) {
          if (l == 0) dout[(size_t)b * CH + c] = val;
        } else {
          int k = 2 * c + par;
          size_t byte = ((size_t)P << 11) + (size_t)((k >> 6) << 7) +
                        ((((k >> 3) & 7) ^ (P & 7)) << 4) + ((k & 7) << 1);
          *(unsigned short*)(outp + byte) = h2u((_Float16)val);
        }
      }
    }
  }
}

// ---------- small levels (5..12, cols <= 128): BK=128, 192x64 tile (r14, proven) ----------
__global__ __launch_bounds__(256, 2) void small_level_k(const float* __restrict__ bias,
                                                        const int* __restrict__ Nvec,
                                                        char* __restrict__ ws,
                                                        float* __restrict__ dout,
                                                        int level, int tiles) {
  __shared__ char smem[131072];  // A: 2 x 49152 @0, B: 2 x 16384 @98304
  const int id = blockIdx.x;
  const int o0 = (id & 7) * 64;
  const int r2 = id >> 3;
  const int xb = r2 % tiles;
  const int b = r2 / tiles;
  if (b >= BATCH) return;

  size_t offC0, offA, offB; int n, nfp2, half;
  layout(Nvec, b, offC0, offA, offB, n, nfp2, half);

  int w = nfp2 >> (level - 1);
  if (w < 2) return;
  const int cols = w >> 1;
  const size_t inOff = (level & 1) ? offA : offB;
  const size_t outOff = (level & 1) ? offB : offA;
  const bool fin = (cols == 1);
  const int l0 = xb * 64;
  if (l0 >= cols) return;

  const int tid = threadIdx.x;
  const int lane = tid & 63, wid = tid >> 6;
  const int lane15 = lane & 15, lq = lane >> 4;
  const int rg = wid & 1, cg = wid >> 1;
  const char* inp = ws + inOff;

  unsigned aoff[12]; int adst[12];
#pragma unroll
  for (int q = 0; q < 12; ++q) {
    int d = q * 4096 + tid * 16;
    int r = d >> 8;                               // tile row 0..191 (256 B rows)
    int p = d & 255;
    int o = ((r >> 6) << 9) + o0 + (r & 63);
    aoff[q] = (unsigned)(p >> 7) * 196608u + ((unsigned)o << 7) + (p & 127);
    adst[q] = q * 4096 + wid * 1024;
  }
  unsigned boff[4]; int bdst[4];
#pragma unroll
  for (int q = 0; q < 4; ++q) {
    int d = q * 4096 + tid * 16;
    int l = d >> 8;                               // col 0..63
    int p = d & 255;
    int lc = l0 + l; if (lc > cols - 1) lc = cols - 1;
    boff[q] = ((unsigned)lc << 11) + (unsigned)((p >> 7) << 7) + (p & 127);
    bdst[q] = q * 4096 + wid * 1024;
  }

#define STAGES(st, sel) do {                                                 \
    char* Ab = smem + (sel) * 49152;                                         \
    char* Bb = smem + 98304 + (sel) * 16384;                                 \
    unsigned ka = (unsigned)(st) * 393216u;                                  \
    unsigned kb = (unsigned)(st) << 8;                                       \
    _Pragma("unroll") for (int q = 0; q < 12; ++q)                           \
      gload16(ws + ka + aoff[q], Ab + adst[q]);                              \
    _Pragma("unroll") for (int q = 0; q < 4; ++q)                            \
      gload16(inp + kb + boff[q], Bb + bdst[q]);                             \
  } while (0)

  f4v acc[6][2];
#pragma unroll
  for (int m = 0; m < 6; ++m)
#pragma unroll
    for (int cf = 0; cf < 2; ++cf) acc[m][cf] = (f4v){0.f, 0.f, 0.f, 0.f};

  STAGES(0, 0);
  __syncthreads();

#pragma unroll 1
  for (int st = 0; st < 8; ++st) {
    const int cur = st & 1;
    if (st + 1 < 8) STAGES(st + 1, cur ^ 1);
    const char* Asb = smem + cur * 49152;
    const char* Bsb = smem + 98304 + cur * 16384;

#pragma unroll
    for (int sub = 0; sub < 2; ++sub) {
#pragma unroll
      for (int s2 = 0; s2 < 2; ++s2) {
        const int oct = (s2 << 2) | lq;
        h8v bh[2];
#pragma unroll
        for (int cf = 0; cf < 2; ++cf) {
          int ll = cg * 32 + cf * 16 + lane15;
          bh[cf] = *(const h8v*)(Bsb + ll * 256 + sub * 128 + ((oct ^ (ll & 7)) << 4));
        }
#pragma unroll
        for (int m = 0; m < 6; ++m) {
          int rr = (m >> 1) * 64 + rg * 32 + (m & 1) * 16 + lane15;
          h8v ah = *(const h8v*)(Asb + rr * 256 + sub * 128 + ((oct ^ (rr & 7)) << 4));
#pragma unroll
          for (int cf = 0; cf < 2; ++cf)
            acc[m][cf] = __builtin_amdgcn_mfma_f32_16x16x32_f16(ah, bh[cf], acc[m][cf], 0, 0, 0);
        }
      }
    }
    __syncthreads();
  }
#undef STAGES

  char* outp = ws + outOff;
#pragma unroll
  for (int s = 0; s < 2; ++s) {
#pragma unroll
    for (int cf = 0; cf < 2; ++cf) {
      f4v vl = acc[s][cf], vr = acc[2 + s][cf], vg = acc[4 + s][cf];
      int l = l0 + cg * 32 + cf * 16 + lane15;
      if (l >= cols) continue;
      int P = l >> 1, par = l & 1;
#pragma unroll
      for (int j = 0; j < 4; ++j) {
        int c = o0 + rg * 32 + s * 16 + lq * 4 + j;
        float zl = vl[j] + bias[c];
        float zr = vr[j] + bias[CH + c];
        float zg = vg[j] + bias[2 * CH + c];
        float g = 1.f / (1.f + __expf(-zg));
        float rt = 1.f - 2.f / (1.f + __expf(2.f * zr));
        float val = zl * g + rt * (1.f - g);
        if (fin) {
          if (l == 0) dout[(size_t)b * CH + c] = val;
        } else {
          int k = 2 * c + par;
          size_t byte = ((size_t)P << 11) + (size_t)((k >> 6) << 7) +
                        ((((k >> 3) & 7) ^ (P & 7)) << 4) + ((k & 7) << 1);
          *(unsigned short*)(outp + byte) = h2u((_Float16)val);
        }
      }
    }
  }
}

extern "C" void kernel_launch(void* const* d_in, const int* in_sizes, int n_in,
                              void* d_out, int out_size, void* d_ws, size_t ws_size,
                              hipStream_t stream) {
  const float* h = (const float*)d_in[0];
  const float* W = (const float*)d_in[1];
  const float* bias = (const float*)d_in[2];
  const int* Nvec = (const int*)d_in[3];
  float* dout = (float*)d_out;
  char* ws = (char*)d_ws;

  prep_w_k<<<dim3(96), 256, 0, stream>>>(W, ws);
  reorg_h_k<<<dim3(128, 8, BATCH), 256, 0, stream>>>(h, Nvec, ws, dout);

  // level 0: max half = 952 -> 8 tiles of 128
  mfma_level_k<<<dim3(8 * 8 * BATCH), 256, 0, stream>>>(bias, Nvec, ws, dout, 0, 8);
  // big tree levels 1..4 (cols up to 2048)
  for (int lev = 1; lev <= 4; ++lev) {
    int tiles = (LMAX >> lev) / 128;
    mfma_level_k<<<dim3(tiles * 8 * BATCH), 256, 0, stream>>>(bias, Nvec, ws, dout, lev, tiles);
  }
  // small tree levels 5..12 (cols <= 128): BK=128 kernel, 64-col tiles
  for (int lev = 5; lev <= 12; ++lev) {
    int colsmax = LMAX >> lev;
    int tiles = (colsmax + 63) / 64; if (tiles < 1) tiles = 1;
    small_level_k<<<dim3(tiles * 8 * BATCH), 256, 0, stream>>>(bias, Nvec, ws, dout, lev, tiles);
  }
}